// Round 2
// baseline (330.329 us; speedup 1.0000x reference)
//
#include <hip/hip_runtime.h>

// Retention, B=4 S=4096 H=1024, gamma=0.96875.
// out[b,i,:] = sum_{j<=i} gamma^(i-j) * (q_i . k_j) * v_j
//
// Pipeline:
//   x~   = [x | 1 | 0pad63]               (16384 x 1088 bf16)
//   W~qT = [Wq^T ; bq ; 0pad]             (1152 x 1024)   W~kT same, padded to 1280 rows
//   P1   = W~kT . W~qT^T                  (1280 x 1088)   (128^2 kernel, hidden under cvt_x)
//   G    = x~ . P1^T                      (16384 x 1280, cols >=1088 are 0, clipped store)
//   Vt   = (Wv . x~^T) scattered          ([b][h][s] bf16)
//   Pb   = band(G . x~^T) * gamma^d       (64 qtiles x 256 x 768 bf16, 3 key-slots of 256)
//   out  = Pb . Vt^T (K=768 banded)       (f32)
// Band window 512..767 (>= old 512); truncated tail < 1e-5 << threshold.
//
// R2 change: all 4 big GEMMs moved from the 128^2 2-barrier structure (measured
// ~616 TF = the 2-phase ceiling, MfmaUtil 25%) to a 256x256 8-wave counted-vmcnt
// slice-ring kernel (T3+T4), with T2 both-sides LDS swizzle (ch ^= (row>>1)&3,
// 8-way -> 2-way/free) and T5 setprio around the MFMA cluster.
//   - K streamed as 32-wide slices through a ring of 4 LDS slots (128 KB, 1 blk/CU),
//     staged 3 ahead; per phase: STAGE(ks+3); vmcnt(12); bar; 12x ds_read_b128;
//     32 MFMA; bar.  vmcnt never 0 in the main loop (drain 8/4/0 in 3 tail phases).
//   - Pb dead band regions pre-zeroed so `out` runs uniform K=768.

typedef __attribute__((ext_vector_type(8))) short short8;   // 8 bf16 = 4 VGPRs
typedef __attribute__((ext_vector_type(4))) float floatx4;  // MFMA 16x16 C/D

#define MFMA(a, b, c) __builtin_amdgcn_mfma_f32_16x16x32_bf16((a), (b), (c), 0, 0, 0)

#define B_SZ   4
#define S_LEN  4096
#define H_DIM  1024
#define NROWS  (B_SZ * S_LEN)          // 16384
#define HP     1088                    // padded H+1 (17*64)
#define LOG2G  (-0.045803690f)         // log2(0.96875)

__device__ __forceinline__ unsigned short f32_to_bf16_rn(float f) {
    unsigned int u = __float_as_uint(f);
    u += 0x7FFFu + ((u >> 16) & 1u);   // round-to-nearest-even
    return (unsigned short)(u >> 16);
}

#define GLOAD_LDS16(gptr, lptr)                                                        \
    __builtin_amdgcn_global_load_lds((__attribute__((address_space(1))) void*)(gptr),  \
                                     (__attribute__((address_space(3))) void*)(lptr),  \
                                     16, 0, 0)

#define BAR()                                   \
    do {                                        \
        asm volatile("" ::: "memory");          \
        __builtin_amdgcn_s_barrier();           \
        asm volatile("" ::: "memory");          \
    } while (0)

// ---------------------------------------------------------------- elementwise bodies
__device__ __forceinline__ void cvt_bf16_body(int i, const float* __restrict__ src,
                                              unsigned short* __restrict__ dst, int n4) {
    if (i >= n4) return;
    float4 v = ((const float4*)src)[i];
    ushort4 o;
    o.x = f32_to_bf16_rn(v.x);
    o.y = f32_to_bf16_rn(v.y);
    o.z = f32_to_bf16_rn(v.z);
    o.w = f32_to_bf16_rn(v.w);
    ((ushort4*)dst)[i] = o;
}

// x -> x~ rows of HP (cols 0..1023)
__device__ __forceinline__ void cvt_x_body(int idx, const float* __restrict__ src,
                                           unsigned short* __restrict__ dst) {
    int row = idx >> 7, c8 = (idx & 127) * 8;
    const float4* s = (const float4*)(src + (size_t)row * H_DIM + c8);
    float4 a = s[0], b = s[1];
    ushort4 o0, o1;
    o0.x = f32_to_bf16_rn(a.x); o0.y = f32_to_bf16_rn(a.y);
    o0.z = f32_to_bf16_rn(a.z); o0.w = f32_to_bf16_rn(a.w);
    o1.x = f32_to_bf16_rn(b.x); o1.y = f32_to_bf16_rn(b.y);
    o1.z = f32_to_bf16_rn(b.z); o1.w = f32_to_bf16_rn(b.w);
    ushort4* d = (ushort4*)(dst + (size_t)row * HP + c8);
    d[0] = o0; d[1] = o1;
}

// cols 1024..1087 of x~: 1.0 at col 1024, zeros elsewhere  (idx over 16384*8)
__device__ __forceinline__ void fill_pad_body(int idx, unsigned short* __restrict__ dst) {
    int row = idx >> 3, c = idx & 7;
    uint4 v; v.x = (c == 0) ? 0x00003F80u : 0u; v.y = 0u; v.z = 0u; v.w = 0u;
    *(uint4*)(dst + (size_t)row * HP + 1024 + c * 8) = v;
}

// zero the never-written band regions of pb: per batch, qtile ql=0 cols 0..511,
// ql=1 cols 0..255.  12 regions of 256x256, idx over 12*8192.
__device__ __forceinline__ void zero_pb_body(int idx, unsigned short* __restrict__ pb) {
    int r = idx >> 13;
    int rem = idx & 8191;
    int row = rem >> 5, c8 = (rem & 31) * 8;
    int batch = r / 3, sub = r % 3;
    int qt = batch * 16 + (sub == 2 ? 1 : 0);
    int col0 = (sub == 2 ? 0 : sub * 256);
    uint4 z; z.x = 0u; z.y = 0u; z.z = 0u; z.w = 0u;
    *(uint4*)(pb + (size_t)qt * (256 * 768) + (size_t)row * 768 + col0 + c8) = z;
}

// W (f32) + bias -> [W^T ; bias ; 0] bf16, nrows x 1024.  (bx in [0,8), by in [0,nby))
__device__ __forceinline__ void tr_cvt_body(float (&Lt)[128][33],
                                            const float* __restrict__ Wsrc,
                                            const float* __restrict__ bias,
                                            unsigned short* __restrict__ dst,
                                            int bx, int by, int tid) {
    if (by >= 32) {                                // rows >=1024: bias row + zeros
        if (bx != 0) return;
        const int h0 = by * 32;
#pragma unroll
        for (int i = 0; i < 128; ++i) {
            int idx = i * 256 + tid;               // 32*1024
            int r = idx >> 10, cc = idx & 1023;
            int h = h0 + r;
            float v = (h == 1024) ? bias[cc] : 0.0f;
            dst[(size_t)h * 1024 + cc] = f32_to_bf16_rn(v);
        }
        return;
    }
    const int w0 = bx * 128, h0 = by * 32;
#pragma unroll
    for (int i = 0; i < 16; ++i) {
        int idx = i * 256 + tid;
        int r = idx >> 5, cc = idx & 31;
        Lt[r][cc] = Wsrc[(size_t)(w0 + r) * 1024 + h0 + cc];
    }
    __syncthreads();
#pragma unroll
    for (int i = 0; i < 16; ++i) {
        int idx = i * 256 + tid;
        int hh = idx >> 7, ww = idx & 127;
        dst[(size_t)(h0 + hh) * 1024 + w0 + ww] = f32_to_bf16_rn(Lt[ww][hh]);
    }
}

// ---------------------------------------------------------------- 128x128 GEMM (P1 only)
__device__ __forceinline__ void gemm_body128(unsigned short (&As)[2][128 * 32],
                                             unsigned short (&Bs)[2][128 * 32],
                                             int bx, int by,
                                             const unsigned short* __restrict__ A, int lda,
                                             const unsigned short* __restrict__ W, int ldw,
                                             unsigned short* __restrict__ outp, int ldo,
                                             int K, int p0) {
    const int tid  = threadIdx.x;
    const int lane = tid & 63;
    const int w4   = tid >> 6;
    const int wm   = w4 >> 1, wn = w4 & 1;
    const int l15  = lane & 15;
    const int q8   = (lane >> 4) * 8;
    const int q4   = (lane >> 4) * 4;

    const int aRow0 = by * 128, wRow0 = bx * 128;

    floatx4 acc[4][4];
#pragma unroll
    for (int i = 0; i < 4; ++i)
#pragma unroll
        for (int j = 0; j < 4; ++j) acc[i][j] = (floatx4)0.0f;

    for (int k0 = 0; k0 < K; k0 += 64) {
        __syncthreads();
#pragma unroll
        for (int p = 0; p < 2; ++p) {
            const int c = p * 256 + tid;
            const unsigned short* gA = A + (size_t)(aRow0 + (c >> 2)) * lda + k0 + (c & 3) * 8;
            const unsigned short* gW = W + (size_t)(wRow0 + (c >> 2)) * ldw + k0 + (c & 3) * 8;
            char* dA0 = (char*)&As[0][0] + (size_t)(p * 256 + w4 * 64) * 16;
            char* dA1 = (char*)&As[1][0] + (size_t)(p * 256 + w4 * 64) * 16;
            char* dB0 = (char*)&Bs[0][0] + (size_t)(p * 256 + w4 * 64) * 16;
            char* dB1 = (char*)&Bs[1][0] + (size_t)(p * 256 + w4 * 64) * 16;
            GLOAD_LDS16(gA,      dA0);
            GLOAD_LDS16(gA + 32, dA1);
            GLOAD_LDS16(gW,      dB0);
            GLOAD_LDS16(gW + 32, dB1);
        }
        __syncthreads();

#pragma unroll
        for (int h = 0; h < 2; ++h) {
            short8 af[4], bf[4];
#pragma unroll
            for (int mt = 0; mt < 4; ++mt)
                af[mt] = *(const short8*)(&As[h][0] + (wm * 64 + mt * 16 + l15) * 32 + q8);
#pragma unroll
            for (int nt = 0; nt < 4; ++nt)
                bf[nt] = *(const short8*)(&Bs[h][0] + (wn * 64 + nt * 16 + l15) * 32 + q8);
#pragma unroll
            for (int mt = 0; mt < 4; ++mt)
#pragma unroll
                for (int nt = 0; nt < 4; ++nt)
                    acc[mt][nt] = MFMA(af[mt], bf[nt], acc[mt][nt]);
        }
    }

#pragma unroll
    for (int nt = 0; nt < 4; ++nt) {
        const int ol = wn * 64 + nt * 16 + l15;
#pragma unroll
        for (int mt = 0; mt < 4; ++mt) {
#pragma unroll
            for (int r = 0; r < 4; ++r) {
                const int nl = wm * 64 + mt * 16 + q4 + r;
                const int o = wRow0 + ol;
                if (o < p0)
                    outp[(size_t)(aRow0 + nl) * ldo + o] = f32_to_bf16_rn(acc[mt][nt][r]);
            }
        }
    }
}

// ---------------------------------------------------------------- 256x256 8-wave slice-ring GEMM
// C[m,n] = sum_k A[m,k]*W[n,k].  K streamed as NS slices of 32; ring of 4 LDS slots
// (A 256x32 + B 256x32 = 32 KB each); staged 3 ahead, 4 global_load_lds/thread/slice.
// Per phase: STAGE(ks+3); vmcnt(12); bar; 12x ds_read_b128 (T2-swizzled); 32 MFMA
// (setprio 1); bar.  Tail drains vmcnt 8/4/0.  8 waves as 2M x 4N, 128x64 per wave.
// MODE 0: G   (bf16 store, col-clip 1088, ldo 1088)
// MODE 1: Vt  (scatter to [b][h][s]; bx=h-tile, by=s-tile)
// MODE 2: Pb  (decay epilogue -> band [qt][256][768]; bx=slot 0..2, by=qt)
// MODE 3: out (f32 store; bx=h-tile, by=qt; A=pb banded, W=vtb offset by (ql-2)*256)
template <int MODE, int NS>
__device__ __forceinline__ void g256_body(unsigned short (&lds)[4][2][8192],
                                          int bx, int by,
                                          const unsigned short* __restrict__ Abase, int lda,
                                          const unsigned short* __restrict__ Wbase, int ldw,
                                          void* __restrict__ outp) {
    const int tid  = threadIdx.x;
    const int lane = tid & 63;
    const int wv   = tid >> 6;         // 0..7
    const int wm   = wv >> 2, wn = wv & 3;
    const int l15  = lane & 15;
    const int q    = lane >> 4;        // 0..3 (which 8-col chunk of the 32-k slice)
    const int q4   = q * 4;

    const unsigned short* Ap;
    const unsigned short* Wp;
    int ql = 0;
    if (MODE == 0) {
        Ap = Abase + (size_t)(by * 256) * lda;
        Wp = Wbase + (size_t)(bx * 256) * ldw;
    } else if (MODE == 1) {
        Ap = Abase + (size_t)(bx * 256) * lda;         // h-tile
        Wp = Wbase + (size_t)(by * 256) * ldw;         // s-tile
    } else if (MODE == 2) {
        ql = by & 15;
        const int j256 = ql - 2 + bx;
        if (j256 < 0) return;                           // block-uniform early exit
        Ap = Abase + (size_t)(by * 256) * lda;
        Wp = Wbase + (size_t)((by >> 4) * S_LEN + j256 * 256) * ldw;
    } else {                                            // MODE 3
        ql = by & 15;
        Ap = Abase + (size_t)by * (256 * 768);
        Wp = Wbase + ((ptrdiff_t)((by >> 4) * H_DIM + bx * 256)) * S_LEN
                   + ((ptrdiff_t)ql - 2) * 256;         // may be negative: reads x Pb zeros
    }

    // staging geometry: chunk c = i*512+tid ; row=c>>2 ; swizzled src chunk (T2, rule 21:
    // linear LDS dest, inverse-swizzled global source, swizzled read)
    int arow[2], ach[2];
#pragma unroll
    for (int i = 0; i < 2; ++i) {
        int c  = i * 512 + tid;
        arow[i] = c >> 2;
        ach[i]  = (((c & 3) ^ ((c >> 3) & 3))) * 8;
    }

    floatx4 acc[8][4];
#pragma unroll
    for (int i = 0; i < 8; ++i)
#pragma unroll
        for (int j = 0; j < 4; ++j) acc[i][j] = (floatx4)0.0f;

    auto STAGE = [&](int ks) {
        const int sl = ks & 3;
        const int kc = ks * 32;
        char* da = (char*)&lds[sl][0][0] + (size_t)(wv * 64) * 16;
        char* db = (char*)&lds[sl][1][0] + (size_t)(wv * 64) * 16;
#pragma unroll
        for (int i = 0; i < 2; ++i) {
            GLOAD_LDS16(Ap + (size_t)arow[i] * lda + kc + ach[i], da + i * 8192);
            GLOAD_LDS16(Wp + (size_t)arow[i] * ldw + kc + ach[i], db + i * 8192);
        }
    };

    auto COMPUTE = [&](int ks) {
        const int sl = ks & 3;
        const unsigned short* Asl = &lds[sl][0][0];
        const unsigned short* Bsl = &lds[sl][1][0];
        short8 af[8], bf[4];
#pragma unroll
        for (int mt = 0; mt < 8; ++mt) {
            const int row = wm * 128 + mt * 16 + l15;
            af[mt] = *(const short8*)(Asl + row * 32 + ((q ^ ((row >> 1) & 3)) * 8));
        }
#pragma unroll
        for (int nt = 0; nt < 4; ++nt) {
            const int row = wn * 64 + nt * 16 + l15;
            bf[nt] = *(const short8*)(Bsl + row * 32 + ((q ^ ((row >> 1) & 3)) * 8));
        }
        __builtin_amdgcn_s_setprio(1);
#pragma unroll
        for (int mt = 0; mt < 8; ++mt)
#pragma unroll
            for (int nt = 0; nt < 4; ++nt)
                acc[mt][nt] = MFMA(af[mt], bf[nt], acc[mt][nt]);
        __builtin_amdgcn_s_setprio(0);
    };

    // prologue: 3 slices in flight
    STAGE(0); STAGE(1); STAGE(2);

    int ks = 0;
#pragma unroll 1
    for (; ks < NS - 3; ++ks) {
        STAGE(ks + 3);                                   // slot (ks-1)&3, freed by prev phase
        asm volatile("s_waitcnt vmcnt(12)" ::: "memory"); // slice ks landed (per-wave)
        BAR();                                            // all waves' slice ks landed
        COMPUTE(ks);
        BAR();                                            // all reads of slot done before restage
    }
    // drain: 3 tail phases, vmcnt 8 / 4 / 0
    asm volatile("s_waitcnt vmcnt(8)" ::: "memory");
    BAR();
    COMPUTE(ks);
    BAR();
    asm volatile("s_waitcnt vmcnt(4)" ::: "memory");
    BAR();
    COMPUTE(ks + 1);
    BAR();
    asm volatile("s_waitcnt vmcnt(0)" ::: "memory");
    BAR();
    COMPUTE(ks + 2);

    // ---- epilogue (C/D layout: col=lane&15, row=(lane>>4)*4+r)
#pragma unroll
    for (int nt = 0; nt < 4; ++nt) {
        const int ol = wn * 64 + nt * 16 + l15;          // n-local 0..255
#pragma unroll
        for (int mt = 0; mt < 8; ++mt) {
#pragma unroll
            for (int r = 0; r < 4; ++r) {
                const int nl = wm * 128 + mt * 16 + q4 + r;   // m-local 0..255
                const float v = acc[mt][nt][r];
                if (MODE == 0) {
                    const int o = bx * 256 + ol;
                    if (o < HP)
                        ((unsigned short*)outp)[(size_t)(by * 256 + nl) * HP + o] =
                            f32_to_bf16_rn(v);
                } else if (MODE == 1) {
                    const int s  = by * 256 + ol;
                    const int hh = bx * 256 + nl;
                    ((unsigned short*)outp)[((size_t)(s >> 12) * H_DIM + hh) * S_LEN +
                                            (s & (S_LEN - 1))] = f32_to_bf16_rn(v);
                } else if (MODE == 2) {
                    const int d = (2 - bx) * 256 + nl - ol;
                    const float pv = (d >= 0) ? v * exp2f((float)d * LOG2G) : 0.0f;
                    ((unsigned short*)outp)[(size_t)by * (256 * 768) + (size_t)nl * 768 +
                                            bx * 256 + ol] = f32_to_bf16_rn(pv);
                } else {
                    ((float*)outp)[(size_t)(by * 256 + nl) * H_DIM + bx * 256 + ol] = v;
                }
            }
        }
    }
}

// ---------------------------------------------------------------- launches
// L1: all prep: tr_cvt(Wq 1152r), tr_cvt(Wk 1280r), cvt Wv, zero pb band, x~ pad cols
__global__ __launch_bounds__(256) void prep_small(const float* __restrict__ Wq,
                                                  const float* __restrict__ bq,
                                                  const float* __restrict__ Wk,
                                                  const float* __restrict__ bk,
                                                  const float* __restrict__ Wv,
                                                  unsigned short* __restrict__ wqT,
                                                  unsigned short* __restrict__ wkT,
                                                  unsigned short* __restrict__ wvb,
                                                  unsigned short* __restrict__ pb,
                                                  unsigned short* __restrict__ xtb) {
    __shared__ float Lt[128][33];
    const int t = blockIdx.x, tid = threadIdx.x;
    if (t < 288) {
        tr_cvt_body(Lt, Wq, bq, wqT, t & 7, t >> 3, tid);             // by 0..35
    } else if (t < 608) {
        const int t2 = t - 288;
        tr_cvt_body(Lt, Wk, bk, wkT, t2 & 7, t2 >> 3, tid);           // by 0..39
    } else if (t < 1632) {
        cvt_bf16_body((t - 608) * 256 + tid, Wv, wvb, H_DIM * H_DIM / 4);
    } else if (t < 2016) {
        zero_pb_body((t - 1632) * 256 + tid, pb);
    } else {
        fill_pad_body((t - 2016) * 256 + tid, xtb);
    }
}

// L2: P1 (90 latency-bound blocks, first) ∪ cvt_x (8192 streaming blocks hide it)
__global__ __launch_bounds__(256) void cvtx_p1(const float* __restrict__ x,
                                               unsigned short* __restrict__ xtb,
                                               const unsigned short* __restrict__ wkT,
                                               const unsigned short* __restrict__ wqT,
                                               unsigned short* __restrict__ p1) {
    __shared__ unsigned short As[2][128 * 32];
    __shared__ unsigned short Bs[2][128 * 32];
    const int t = blockIdx.x;
    if (t < 90) {
        // P1 = W~kT . W~qT^T  (1280 x 1152 clipped to 1088 cols, K=1024)
        gemm_body128(As, Bs, t % 9, t / 9, wkT, 1024, wqT, 1024, p1, HP, 1024, HP);
    } else {
        cvt_x_body((t - 90) * 256 + threadIdx.x, x, xtb);
    }
}

// L3: G = x~ . P1^T  (16384 x 1280 -> clip 1088, K=1088 = 34 slices), XCD-swizzled
__global__ __launch_bounds__(512, 2) void g256_g(const unsigned short* __restrict__ xtb,
                                                 const unsigned short* __restrict__ p1,
                                                 unsigned short* __restrict__ gb) {
    __shared__ unsigned short lds[4][2][8192];
    const int bid = blockIdx.x;                 // 320 = 8 * 40
    const int g = bid & 7, j = bid >> 3;
    g256_body<0, 34>(lds, j % 5, g * 8 + j / 5, xtb, HP, p1, HP, gb);
}

// L4: Pb (192 blocks, latency-exposed — first) ∪ Vt (256 blocks behind them)
__global__ __launch_bounds__(512, 2) void g256_pbvt(const unsigned short* __restrict__ gb,
                                                    const unsigned short* __restrict__ xtb,
                                                    const unsigned short* __restrict__ wvb,
                                                    unsigned short* __restrict__ pb,
                                                    unsigned short* __restrict__ vtb) {
    __shared__ unsigned short lds[4][2][8192];
    const int t = blockIdx.x;
    if (t < 192) {
        // Pb = band(G . x~^T) * gamma^d  (3 slots of 256 per q-tile, K=1088)
        const int g = t & 7, j = t >> 3;        // 192 = 8 * 24
        g256_body<2, 34>(lds, j % 3, g * 8 + j / 3, gb, HP, xtb, HP, pb);
    } else {
        // Vt = Wv . x~^T scattered to [b][h][s]  (K=1024 = 32 slices)
        const int t2 = t - 192;
        const int g = t2 & 7, j = t2 >> 3;      // 256 = 8 * 32
        g256_body<1, 32>(lds, j & 3, g * 8 + (j >> 2), wvb, 1024, xtb, HP, vtb);
    }
}

// L5: out = Pb . Vt^T  (K=768 = 24 slices, f32)
__global__ __launch_bounds__(512, 2) void g256_out(const unsigned short* __restrict__ pb,
                                                   const unsigned short* __restrict__ vtb,
                                                   float* __restrict__ out) {
    __shared__ unsigned short lds[4][2][8192];
    const int bid = blockIdx.x;                 // 256 = 8 * 32
    const int g = bid & 7, j = bid >> 3;
    g256_body<3, 24>(lds, j & 3, g * 8 + (j >> 2), pb, 768, vtb, S_LEN, out);
}

// ---------------------------------------------------------------- launcher
extern "C" void kernel_launch(void* const* d_in, const int* in_sizes, int n_in,
                              void* d_out, int out_size, void* d_ws, size_t ws_size,
                              hipStream_t stream) {
    (void)in_sizes; (void)n_in; (void)out_size; (void)ws_size;

    const float* x  = (const float*)d_in[0];
    const float* Wq = (const float*)d_in[1];
    const float* bq = (const float*)d_in[2];
    const float* Wk = (const float*)d_in[3];
    const float* bk = (const float*)d_in[4];
    const float* Wv = (const float*)d_in[5];
    float* out = (float*)d_out;

    unsigned short* xtb = (unsigned short*)d_ws;                    // 16384*1088*2 = 35.7 MB
    unsigned short* gb  = xtb + (size_t)NROWS * HP;                 // 35.7 MB
    unsigned short* vtb = gb  + (size_t)NROWS * HP;                 // 33.6 MB
    unsigned short* pb  = vtb + (size_t)NROWS * H_DIM;              // 64*256*768*2 = 25.2 MB
    unsigned short* wqT = pb  + (size_t)64 * 256 * 768;             // 1152*1024*2 = 2.36 MB
    unsigned short* wkT = wqT + (size_t)1152 * 1024;                // 1280*1024*2 = 2.62 MB
    unsigned short* p1  = wkT + (size_t)1280 * 1024;                // 1280*1088*2 = 2.79 MB
    unsigned short* wvb = p1  + (size_t)1280 * HP;                  // 2.1 MB
    // total ~= 140 MB

    prep_small<<<2528, 256, 0, stream>>>(Wq, bq, Wk, bk, Wv, wqT, wkT, wvb, pb, xtb);
    cvtx_p1<<<90 + 8192, 256, 0, stream>>>(x, xtb, wkT, wqT, p1);
    g256_g<<<320, 512, 0, stream>>>(xtb, p1, gb);
    g256_pbvt<<<192 + 256, 512, 0, stream>>>(gb, xtb, wvb, pb, vtb);
    g256_out<<<256, 512, 0, stream>>>(pb, vtb, out);
}

// Round 3
// 329.842 us; speedup vs baseline: 1.0015x; 1.0015x over previous
//
#include <hip/hip_runtime.h>

// Retention, B=4 S=4096 H=1024, gamma=0.96875.
// out[b,i,:] = sum_{j<=i} gamma^(i-j) * (q_i . k_j) * v_j
//
// Pipeline:
//   x~   = [x | 1 | 0pad63]               (16384 x 1088 bf16)
//   W~qT = [Wq^T ; bq ; 0pad]             (1152 x 1024)   W~kT same, padded to 1280 rows
//   P1   = W~kT . W~qT^T                  (1280 x 1088)   (128^2 kernel, hidden under cvt_x)
//   G    = x~ . P1^T                      (16384 x 1280, cols >=1088 are 0, clipped store)
//   Vt   = (Wv . x~^T) scattered          ([b][h][s] bf16)
//   Pb   = band(G . x~^T) * gamma^d       (64 qtiles x 256 x 768 bf16, 3 key-slots of 256)
//   out  = Pb . Vt^T (K=768 banded)       (f32)
// Band window 512..767 (>= old 512); truncated tail < 1e-5 << threshold.
//
// R3 change: R2's slice-ring waited vmcnt+2 barriers EVERY 32-K phase with 1 blk/CU
// -> whole CU stalled on per-slice arrival jitter every phase (MfmaUtil 19%, phase
// ~6500cy vs 1242cy of MFMA).  Now m201-shape: K-tiles of 64, 2 LDS buffers (t&1),
// 4 phases/tile x 16 MFMA (quadrants (0,0)(0,1)(1,1)(1,0), A/B reg reuse);
// stage A(t+1) at phase0 / B(t+1) at phase1; ONE counted vmcnt(4) per tile
// (tile t's loads issued 3-4 phases ~2500cy earlier; never drains to 0 mid-loop).
// T2 both-sides swizzle ch^=(row&7) on 128B rows; T5 setprio kept.

typedef __attribute__((ext_vector_type(8))) short short8;   // 8 bf16 = 4 VGPRs
typedef __attribute__((ext_vector_type(4))) float floatx4;  // MFMA 16x16 C/D

#define MFMA(a, b, c) __builtin_amdgcn_mfma_f32_16x16x32_bf16((a), (b), (c), 0, 0, 0)

#define B_SZ   4
#define S_LEN  4096
#define H_DIM  1024
#define NROWS  (B_SZ * S_LEN)          // 16384
#define HP     1088                    // padded H+1 (17*64)
#define LOG2G  (-0.045803690f)         // log2(0.96875)

__device__ __forceinline__ unsigned short f32_to_bf16_rn(float f) {
    unsigned int u = __float_as_uint(f);
    u += 0x7FFFu + ((u >> 16) & 1u);   // round-to-nearest-even
    return (unsigned short)(u >> 16);
}

#define GLOAD_LDS16(gptr, lptr)                                                        \
    __builtin_amdgcn_global_load_lds((__attribute__((address_space(1))) void*)(gptr),  \
                                     (__attribute__((address_space(3))) void*)(lptr),  \
                                     16, 0, 0)

#define BAR()                                   \
    do {                                        \
        asm volatile("" ::: "memory");          \
        __builtin_amdgcn_s_barrier();           \
        asm volatile("" ::: "memory");          \
    } while (0)

// ---------------------------------------------------------------- elementwise bodies
__device__ __forceinline__ void cvt_bf16_body(int i, const float* __restrict__ src,
                                              unsigned short* __restrict__ dst, int n4) {
    if (i >= n4) return;
    float4 v = ((const float4*)src)[i];
    ushort4 o;
    o.x = f32_to_bf16_rn(v.x);
    o.y = f32_to_bf16_rn(v.y);
    o.z = f32_to_bf16_rn(v.z);
    o.w = f32_to_bf16_rn(v.w);
    ((ushort4*)dst)[i] = o;
}

// x -> x~ rows of HP (cols 0..1023)
__device__ __forceinline__ void cvt_x_body(int idx, const float* __restrict__ src,
                                           unsigned short* __restrict__ dst) {
    int row = idx >> 7, c8 = (idx & 127) * 8;
    const float4* s = (const float4*)(src + (size_t)row * H_DIM + c8);
    float4 a = s[0], b = s[1];
    ushort4 o0, o1;
    o0.x = f32_to_bf16_rn(a.x); o0.y = f32_to_bf16_rn(a.y);
    o0.z = f32_to_bf16_rn(a.z); o0.w = f32_to_bf16_rn(a.w);
    o1.x = f32_to_bf16_rn(b.x); o1.y = f32_to_bf16_rn(b.y);
    o1.z = f32_to_bf16_rn(b.z); o1.w = f32_to_bf16_rn(b.w);
    ushort4* d = (ushort4*)(dst + (size_t)row * HP + c8);
    d[0] = o0; d[1] = o1;
}

// cols 1024..1087 of x~: 1.0 at col 1024, zeros elsewhere  (idx over 16384*8)
__device__ __forceinline__ void fill_pad_body(int idx, unsigned short* __restrict__ dst) {
    int row = idx >> 3, c = idx & 7;
    uint4 v; v.x = (c == 0) ? 0x00003F80u : 0u; v.y = 0u; v.z = 0u; v.w = 0u;
    *(uint4*)(dst + (size_t)row * HP + 1024 + c * 8) = v;
}

// zero the never-written band regions of pb: per batch, qtile ql=0 cols 0..511,
// ql=1 cols 0..255.  12 regions of 256x256, idx over 12*8192.
__device__ __forceinline__ void zero_pb_body(int idx, unsigned short* __restrict__ pb) {
    int r = idx >> 13;
    int rem = idx & 8191;
    int row = rem >> 5, c8 = (rem & 31) * 8;
    int batch = r / 3, sub = r % 3;
    int qt = batch * 16 + (sub == 2 ? 1 : 0);
    int col0 = (sub == 2 ? 0 : sub * 256);
    uint4 z; z.x = 0u; z.y = 0u; z.z = 0u; z.w = 0u;
    *(uint4*)(pb + (size_t)qt * (256 * 768) + (size_t)row * 768 + col0 + c8) = z;
}

// W (f32) + bias -> [W^T ; bias ; 0] bf16, nrows x 1024.  (bx in [0,8), by in [0,nby))
__device__ __forceinline__ void tr_cvt_body(float (&Lt)[128][33],
                                            const float* __restrict__ Wsrc,
                                            const float* __restrict__ bias,
                                            unsigned short* __restrict__ dst,
                                            int bx, int by, int tid) {
    if (by >= 32) {                                // rows >=1024: bias row + zeros
        if (bx != 0) return;
        const int h0 = by * 32;
#pragma unroll
        for (int i = 0; i < 128; ++i) {
            int idx = i * 256 + tid;               // 32*1024
            int r = idx >> 10, cc = idx & 1023;
            int h = h0 + r;
            float v = (h == 1024) ? bias[cc] : 0.0f;
            dst[(size_t)h * 1024 + cc] = f32_to_bf16_rn(v);
        }
        return;
    }
    const int w0 = bx * 128, h0 = by * 32;
#pragma unroll
    for (int i = 0; i < 16; ++i) {
        int idx = i * 256 + tid;
        int r = idx >> 5, cc = idx & 31;
        Lt[r][cc] = Wsrc[(size_t)(w0 + r) * 1024 + h0 + cc];
    }
    __syncthreads();
#pragma unroll
    for (int i = 0; i < 16; ++i) {
        int idx = i * 256 + tid;
        int hh = idx >> 7, ww = idx & 127;
        dst[(size_t)(h0 + hh) * 1024 + w0 + ww] = f32_to_bf16_rn(Lt[ww][hh]);
    }
}

// ---------------------------------------------------------------- 128x128 GEMM (P1 only)
__device__ __forceinline__ void gemm_body128(unsigned short (&As)[2][128 * 32],
                                             unsigned short (&Bs)[2][128 * 32],
                                             int bx, int by,
                                             const unsigned short* __restrict__ A, int lda,
                                             const unsigned short* __restrict__ W, int ldw,
                                             unsigned short* __restrict__ outp, int ldo,
                                             int K, int p0) {
    const int tid  = threadIdx.x;
    const int lane = tid & 63;
    const int w4   = tid >> 6;
    const int wm   = w4 >> 1, wn = w4 & 1;
    const int l15  = lane & 15;
    const int q8   = (lane >> 4) * 8;
    const int q4   = (lane >> 4) * 4;

    const int aRow0 = by * 128, wRow0 = bx * 128;

    floatx4 acc[4][4];
#pragma unroll
    for (int i = 0; i < 4; ++i)
#pragma unroll
        for (int j = 0; j < 4; ++j) acc[i][j] = (floatx4)0.0f;

    for (int k0 = 0; k0 < K; k0 += 64) {
        __syncthreads();
#pragma unroll
        for (int p = 0; p < 2; ++p) {
            const int c = p * 256 + tid;
            const unsigned short* gA = A + (size_t)(aRow0 + (c >> 2)) * lda + k0 + (c & 3) * 8;
            const unsigned short* gW = W + (size_t)(wRow0 + (c >> 2)) * ldw + k0 + (c & 3) * 8;
            char* dA0 = (char*)&As[0][0] + (size_t)(p * 256 + w4 * 64) * 16;
            char* dA1 = (char*)&As[1][0] + (size_t)(p * 256 + w4 * 64) * 16;
            char* dB0 = (char*)&Bs[0][0] + (size_t)(p * 256 + w4 * 64) * 16;
            char* dB1 = (char*)&Bs[1][0] + (size_t)(p * 256 + w4 * 64) * 16;
            GLOAD_LDS16(gA,      dA0);
            GLOAD_LDS16(gA + 32, dA1);
            GLOAD_LDS16(gW,      dB0);
            GLOAD_LDS16(gW + 32, dB1);
        }
        __syncthreads();

#pragma unroll
        for (int h = 0; h < 2; ++h) {
            short8 af[4], bf[4];
#pragma unroll
            for (int mt = 0; mt < 4; ++mt)
                af[mt] = *(const short8*)(&As[h][0] + (wm * 64 + mt * 16 + l15) * 32 + q8);
#pragma unroll
            for (int nt = 0; nt < 4; ++nt)
                bf[nt] = *(const short8*)(&Bs[h][0] + (wn * 64 + nt * 16 + l15) * 32 + q8);
#pragma unroll
            for (int mt = 0; mt < 4; ++mt)
#pragma unroll
                for (int nt = 0; nt < 4; ++nt)
                    acc[mt][nt] = MFMA(af[mt], bf[nt], acc[mt][nt]);
        }
    }

#pragma unroll
    for (int nt = 0; nt < 4; ++nt) {
        const int ol = wn * 64 + nt * 16 + l15;
#pragma unroll
        for (int mt = 0; mt < 4; ++mt) {
#pragma unroll
            for (int r = 0; r < 4; ++r) {
                const int nl = wm * 64 + mt * 16 + q4 + r;
                const int o = wRow0 + ol;
                if (o < p0)
                    outp[(size_t)(aRow0 + nl) * ldo + o] = f32_to_bf16_rn(acc[mt][nt][r]);
            }
        }
    }
}

// ---------------------------------------------------------------- 256x256 8-wave K64-tile GEMM
// C[m,n] = sum_k A[m,k]*W[n,k].  K as NT tiles of 64; 2 LDS buffers (t&1), each
// A[256x64] + B[256x64] (32 KB each, 128 KB total).  Per tile: 4 phases of 16 MFMA
// (quadrants (mh,nh) = (0,0),(0,1),(1,1),(1,0); A regs reused across nh, B across mh).
// Stage A(t+1) at phase0 (4 gload_lds/thread), B(t+1) at phase1; single counted
// s_waitcnt vmcnt(4) per tile at phase0 (tile t issued 3-4 phases earlier);
// vmcnt(0) only at the final tile.  T2 swizzle: LDS chunk x of row r holds global
// chunk x^(r&7) (linear LDS dest for gload_lds, inverse-swizzled source, swizzled read).
// MODE 0: G   (bf16 store, col-clip HP)    MODE 1: Vt  (scatter to [b][h][s])
// MODE 2: Pb  (decay epilogue -> band)     MODE 3: out (f32 store, banded K)
template <int MODE, int NT>
__device__ __forceinline__ void g256_body(unsigned short (&lds)[2][2][16384],
                                          int bx, int by,
                                          const unsigned short* __restrict__ Abase, int lda,
                                          const unsigned short* __restrict__ Wbase, int ldw,
                                          void* __restrict__ outp) {
    const int tid  = threadIdx.x;
    const int lane = tid & 63;
    const int wv   = tid >> 6;         // 0..7
    const int wm   = wv >> 2, wn = wv & 3;
    const int l15  = lane & 15;
    const int q    = lane >> 4;        // 0..3 (8-elem chunk within 32-k step)
    const int q4   = q * 4;

    const unsigned short* Ap;
    const unsigned short* Wp;
    int ql = 0;
    if (MODE == 0) {
        Ap = Abase + (size_t)(by * 256) * lda;
        Wp = Wbase + (size_t)(bx * 256) * ldw;
    } else if (MODE == 1) {
        Ap = Abase + (size_t)(bx * 256) * lda;         // h-tile
        Wp = Wbase + (size_t)(by * 256) * ldw;         // s-tile
    } else if (MODE == 2) {
        ql = by & 15;
        const int j256 = ql - 2 + bx;
        if (j256 < 0) return;                           // block-uniform early exit
        Ap = Abase + (size_t)(by * 256) * lda;
        Wp = Wbase + (size_t)((by >> 4) * S_LEN + j256 * 256) * ldw;
    } else {                                            // MODE 3
        ql = by & 15;
        Ap = Abase + (size_t)by * (256 * 768);
        Wp = Wbase + ((ptrdiff_t)((by >> 4) * H_DIM + bx * 256)) * S_LEN
                   + ((ptrdiff_t)ql - 2) * 256;         // may be negative: reads x Pb zeros
    }

    floatx4 acc[8][4];
#pragma unroll
    for (int i = 0; i < 8; ++i)
#pragma unroll
        for (int j = 0; j < 4; ++j) acc[i][j] = (floatx4)0.0f;

    // stage one matrix (256x64 = 2048 chunks of 16B) of tile t into lds[t&1][m].
    // LDS dest linear (chunk c at byte c*16); source chunk = (c&7)^(row&7).
    auto STAGE2 = [&](int t, int m) {
        const int b  = t & 1;
        const int k0 = t * 64;
        const unsigned short* gp = m ? Wp : Ap;
        const int ld = m ? ldw : lda;
        char* base = (char*)&lds[b][m][0];
#pragma unroll
        for (int i = 0; i < 4; ++i) {
            const int c   = i * 512 + tid;
            const int row = c >> 3;
            const int ch  = (c & 7) ^ (row & 7);
            GLOAD_LDS16(gp + (size_t)row * ld + k0 + ch * 8,
                        base + (size_t)(i * 512 + wv * 64) * 16);
        }
    };

    short8 afr[4][2], bfr[2][2];
    auto RDA = [&](int t, int mh) {
        const unsigned short* base = &lds[t & 1][0][0];
#pragma unroll
        for (int mt = 0; mt < 4; ++mt) {
            const int r = wm * 128 + mh * 64 + mt * 16 + l15;
#pragma unroll
            for (int h = 0; h < 2; ++h) {
                const int ch = (h * 4 + q) ^ (r & 7);
                afr[mt][h] = *(const short8*)(base + r * 64 + ch * 8);
            }
        }
    };
    auto RDB = [&](int t, int nh) {
        const unsigned short* base = &lds[t & 1][1][0];
#pragma unroll
        for (int nt = 0; nt < 2; ++nt) {
            const int r = wn * 64 + (nh * 2 + nt) * 16 + l15;
#pragma unroll
            for (int h = 0; h < 2; ++h) {
                const int ch = (h * 4 + q) ^ (r & 7);
                bfr[nt][h] = *(const short8*)(base + r * 64 + ch * 8);
            }
        }
    };
    auto QMFMA = [&](int mh, int nh) {
        __builtin_amdgcn_s_setprio(1);
#pragma unroll
        for (int mt = 0; mt < 4; ++mt)
#pragma unroll
            for (int nt = 0; nt < 2; ++nt)
#pragma unroll
                for (int h = 0; h < 2; ++h)
                    acc[mh * 4 + mt][nh * 2 + nt] =
                        MFMA(afr[mt][h], bfr[nt][h], acc[mh * 4 + mt][nh * 2 + nt]);
        __builtin_amdgcn_s_setprio(0);
    };

    // prologue: tile 0 fully issued
    STAGE2(0, 0);
    STAGE2(0, 1);

#pragma unroll 1
    for (int t = 0; t < NT; ++t) {
        // phase 0: stage A(t+1); wait tile t resident (counted); quadrant (0,0)
        if (t + 1 < NT) {
            STAGE2(t + 1, 0);
            asm volatile("s_waitcnt vmcnt(4)" ::: "memory");
        } else {
            asm volatile("s_waitcnt vmcnt(0)" ::: "memory");
        }
        BAR();                         // all waves see tile t in LDS
        RDA(t, 0);
        RDB(t, 0);
        BAR();
        QMFMA(0, 0);
        BAR();
        // phase 1: stage B(t+1); quadrant (0,1)
        if (t + 1 < NT) STAGE2(t + 1, 1);
        RDB(t, 1);
        BAR();
        QMFMA(0, 1);
        BAR();
        // phase 2: quadrant (1,1)
        RDA(t, 1);
        BAR();
        QMFMA(1, 1);
        BAR();
        // phase 3: quadrant (1,0)
        RDB(t, 0);
        BAR();
        QMFMA(1, 0);
        BAR();                         // WAR guard for next tile's STAGE2
    }

    // ---- epilogue (C/D layout: col=lane&15, row=(lane>>4)*4+r)
#pragma unroll
    for (int nt = 0; nt < 4; ++nt) {
        const int ol = wn * 64 + nt * 16 + l15;          // n-local 0..255
#pragma unroll
        for (int mt = 0; mt < 8; ++mt) {
#pragma unroll
            for (int r = 0; r < 4; ++r) {
                const int nl = wm * 128 + mt * 16 + q4 + r;   // m-local 0..255
                const float v = acc[mt][nt][r];
                if (MODE == 0) {
                    const int o = bx * 256 + ol;
                    if (o < HP)
                        ((unsigned short*)outp)[(size_t)(by * 256 + nl) * HP + o] =
                            f32_to_bf16_rn(v);
                } else if (MODE == 1) {
                    const int s  = by * 256 + ol;
                    const int hh = bx * 256 + nl;
                    ((unsigned short*)outp)[((size_t)(s >> 12) * H_DIM + hh) * S_LEN +
                                            (s & (S_LEN - 1))] = f32_to_bf16_rn(v);
                } else if (MODE == 2) {
                    const int d = (2 - bx) * 256 + nl - ol;
                    const float pv = (d >= 0) ? v * exp2f((float)d * LOG2G) : 0.0f;
                    ((unsigned short*)outp)[(size_t)by * (256 * 768) + (size_t)nl * 768 +
                                            bx * 256 + ol] = f32_to_bf16_rn(pv);
                } else {
                    ((float*)outp)[(size_t)(by * 256 + nl) * H_DIM + bx * 256 + ol] = v;
                }
            }
        }
    }
}

// ---------------------------------------------------------------- launches
// L1: all prep: tr_cvt(Wq 1152r), tr_cvt(Wk 1280r), cvt Wv, zero pb band, x~ pad cols
__global__ __launch_bounds__(256) void prep_small(const float* __restrict__ Wq,
                                                  const float* __restrict__ bq,
                                                  const float* __restrict__ Wk,
                                                  const float* __restrict__ bk,
                                                  const float* __restrict__ Wv,
                                                  unsigned short* __restrict__ wqT,
                                                  unsigned short* __restrict__ wkT,
                                                  unsigned short* __restrict__ wvb,
                                                  unsigned short* __restrict__ pb,
                                                  unsigned short* __restrict__ xtb) {
    __shared__ float Lt[128][33];
    const int t = blockIdx.x, tid = threadIdx.x;
    if (t < 288) {
        tr_cvt_body(Lt, Wq, bq, wqT, t & 7, t >> 3, tid);             // by 0..35
    } else if (t < 608) {
        const int t2 = t - 288;
        tr_cvt_body(Lt, Wk, bk, wkT, t2 & 7, t2 >> 3, tid);           // by 0..39
    } else if (t < 1632) {
        cvt_bf16_body((t - 608) * 256 + tid, Wv, wvb, H_DIM * H_DIM / 4);
    } else if (t < 2016) {
        zero_pb_body((t - 1632) * 256 + tid, pb);
    } else {
        fill_pad_body((t - 2016) * 256 + tid, xtb);
    }
}

// L2: P1 (90 latency-bound blocks, first) ∪ cvt_x (8192 streaming blocks hide it)
__global__ __launch_bounds__(256) void cvtx_p1(const float* __restrict__ x,
                                               unsigned short* __restrict__ xtb,
                                               const unsigned short* __restrict__ wkT,
                                               const unsigned short* __restrict__ wqT,
                                               unsigned short* __restrict__ p1) {
    __shared__ unsigned short As[2][128 * 32];
    __shared__ unsigned short Bs[2][128 * 32];
    const int t = blockIdx.x;
    if (t < 90) {
        // P1 = W~kT . W~qT^T  (1280 x 1152 clipped to 1088 cols, K=1024)
        gemm_body128(As, Bs, t % 9, t / 9, wkT, 1024, wqT, 1024, p1, HP, 1024, HP);
    } else {
        cvt_x_body((t - 90) * 256 + threadIdx.x, x, xtb);
    }
}

// L3: G = x~ . P1^T  (16384 x 1280 -> clip 1088, K=1088 = 17 tiles), XCD-swizzled
__global__ __launch_bounds__(512, 2) void g256_g(const unsigned short* __restrict__ xtb,
                                                 const unsigned short* __restrict__ p1,
                                                 unsigned short* __restrict__ gb) {
    __shared__ unsigned short lds[2][2][16384];
    const int bid = blockIdx.x;                 // 320 = 8 * 40
    const int g = bid & 7, j = bid >> 3;
    g256_body<0, 17>(lds, j % 5, g * 8 + j / 5, xtb, HP, p1, HP, gb);
}

// L4: Pb (192 blocks, latency-exposed — first) ∪ Vt (256 blocks behind them)
__global__ __launch_bounds__(512, 2) void g256_pbvt(const unsigned short* __restrict__ gb,
                                                    const unsigned short* __restrict__ xtb,
                                                    const unsigned short* __restrict__ wvb,
                                                    unsigned short* __restrict__ pb,
                                                    unsigned short* __restrict__ vtb) {
    __shared__ unsigned short lds[2][2][16384];
    const int t = blockIdx.x;
    if (t < 192) {
        // Pb = band(G . x~^T) * gamma^d  (3 slots of 256 per q-tile, K=1088)
        const int g = t & 7, j = t >> 3;        // 192 = 8 * 24
        g256_body<2, 17>(lds, j % 3, g * 8 + j / 3, gb, HP, xtb, HP, pb);
    } else {
        // Vt = Wv . x~^T scattered to [b][h][s]  (K=1024 = 16 tiles)
        const int t2 = t - 192;
        const int g = t2 & 7, j = t2 >> 3;      // 256 = 8 * 32
        g256_body<1, 16>(lds, j & 3, g * 8 + (j >> 2), wvb, 1024, xtb, HP, vtb);
    }
}

// L5: out = Pb . Vt^T  (K=768 = 12 tiles, f32)
__global__ __launch_bounds__(512, 2) void g256_out(const unsigned short* __restrict__ pb,
                                                   const unsigned short* __restrict__ vtb,
                                                   float* __restrict__ out) {
    __shared__ unsigned short lds[2][2][16384];
    const int bid = blockIdx.x;                 // 256 = 8 * 32
    const int g = bid & 7, j = bid >> 3;
    g256_body<3, 12>(lds, j & 3, g * 8 + (j >> 2), pb, 768, vtb, S_LEN, out);
}

// ---------------------------------------------------------------- launcher
extern "C" void kernel_launch(void* const* d_in, const int* in_sizes, int n_in,
                              void* d_out, int out_size, void* d_ws, size_t ws_size,
                              hipStream_t stream) {
    (void)in_sizes; (void)n_in; (void)out_size; (void)ws_size;

    const float* x  = (const float*)d_in[0];
    const float* Wq = (const float*)d_in[1];
    const float* bq = (const float*)d_in[2];
    const float* Wk = (const float*)d_in[3];
    const float* bk = (const float*)d_in[4];
    const float* Wv = (const float*)d_in[5];
    float* out = (float*)d_out;

    unsigned short* xtb = (unsigned short*)d_ws;                    // 16384*1088*2 = 35.7 MB
    unsigned short* gb  = xtb + (size_t)NROWS * HP;                 // 35.7 MB
    unsigned short* vtb = gb  + (size_t)NROWS * HP;                 // 33.6 MB
    unsigned short* pb  = vtb + (size_t)NROWS * H_DIM;              // 64*256*768*2 = 25.2 MB
    unsigned short* wqT = pb  + (size_t)64 * 256 * 768;             // 1152*1024*2 = 2.36 MB
    unsigned short* wkT = wqT + (size_t)1152 * 1024;                // 1280*1024*2 = 2.62 MB
    unsigned short* p1  = wkT + (size_t)1280 * 1024;                // 1280*1088*2 = 2.79 MB
    unsigned short* wvb = p1  + (size_t)1280 * HP;                  // 2.1 MB
    // total ~= 140 MB

    prep_small<<<2528, 256, 0, stream>>>(Wq, bq, Wk, bk, Wv, wqT, wkT, wvb, pb, xtb);
    cvtx_p1<<<90 + 8192, 256, 0, stream>>>(x, xtb, wkT, wqT, p1);
    g256_g<<<320, 512, 0, stream>>>(xtb, p1, gb);
    g256_pbvt<<<192 + 256, 512, 0, stream>>>(gb, xtb, wvb, pb, vtb);
    g256_out<<<256, 512, 0, stream>>>(pb, vtb, out);
}

// Round 4
// 329.463 us; speedup vs baseline: 1.0026x; 1.0011x over previous
//
#include <hip/hip_runtime.h>

// Retention, B=4 S=4096 H=1024, gamma=0.96875.
// out[b,i,:] = sum_{j<=i} gamma^(i-j) * (q_i . k_j) * v_j
//
// Pipeline:
//   x~   = [x | 1 | 0pad63]               (16384 x 1088 bf16)
//   W~qT = [Wq^T ; bq ; 0pad]             (1152 x 1024)   W~kT same, padded to 1280 rows
//   P1   = W~kT . W~qT^T                  (1280 x 1088)   (128^2 kernel, hidden under cvt_x)
//   G    = x~ . P1^T                      (16384 x 1280, cols >=1088 are 0, clipped store)
//   Vt   = (Wv . x~^T) scattered          ([b][h][s] bf16)
//   Pb   = band(G . x~^T) * gamma^d       (64 qtiles x 256 x 768 bf16, 3 key-slots of 256)
//   out  = Pb . Vt^T (K=768 banded)       (f32)
// Band window 512..767 (>= old 512); truncated tail < 1e-5 << threshold.
//
// R4 change: R3 sandwiched ds_reads between their own barriers (BAR;RD;BAR;MFMA;BAR,
// 9 bars/tile) -> CU-wide serial read slot, MfmaUtil stuck at 27%.  Now the m201
// phase shape: reads ISSUE BEFORE the leading barrier (latency hides under barrier
// arrival jitter), stage issue rides inside the MFMA slot, 8 bars/tile, ONE counted
// vmcnt(4) per tile at ph4 (ledger: [A(t+1),B(t+1),A(t+2)]=12 -> drains exactly the
// two stages tile t+1 ph1 reads; A(t+2) stays in flight; vmcnt(0) only at t=NT-2).
//   ph1: RD A[q0]+B[q0]; BAR; STAGE B(t+1); MFMA(0,0); BAR
//   ph2: RD B[q1];       BAR;               MFMA(0,1); BAR
//   ph3: RD A[q1];       BAR;               MFMA(1,1); BAR
//   ph4: RD B[q0];       BAR; STAGE A(t+2); MFMA(1,0); vmcnt(4); BAR

typedef __attribute__((ext_vector_type(8))) short short8;   // 8 bf16 = 4 VGPRs
typedef __attribute__((ext_vector_type(4))) float floatx4;  // MFMA 16x16 C/D

#define MFMA(a, b, c) __builtin_amdgcn_mfma_f32_16x16x32_bf16((a), (b), (c), 0, 0, 0)

#define B_SZ   4
#define S_LEN  4096
#define H_DIM  1024
#define NROWS  (B_SZ * S_LEN)          // 16384
#define HP     1088                    // padded H+1 (17*64)
#define LOG2G  (-0.045803690f)         // log2(0.96875)

__device__ __forceinline__ unsigned short f32_to_bf16_rn(float f) {
    unsigned int u = __float_as_uint(f);
    u += 0x7FFFu + ((u >> 16) & 1u);   // round-to-nearest-even
    return (unsigned short)(u >> 16);
}

#define GLOAD_LDS16(gptr, lptr)                                                        \
    __builtin_amdgcn_global_load_lds((__attribute__((address_space(1))) void*)(gptr),  \
                                     (__attribute__((address_space(3))) void*)(lptr),  \
                                     16, 0, 0)

#define BAR()                                   \
    do {                                        \
        asm volatile("" ::: "memory");          \
        __builtin_amdgcn_s_barrier();           \
        asm volatile("" ::: "memory");          \
    } while (0)

// ---------------------------------------------------------------- elementwise bodies
__device__ __forceinline__ void cvt_bf16_body(int i, const float* __restrict__ src,
                                              unsigned short* __restrict__ dst, int n4) {
    if (i >= n4) return;
    float4 v = ((const float4*)src)[i];
    ushort4 o;
    o.x = f32_to_bf16_rn(v.x);
    o.y = f32_to_bf16_rn(v.y);
    o.z = f32_to_bf16_rn(v.z);
    o.w = f32_to_bf16_rn(v.w);
    ((ushort4*)dst)[i] = o;
}

// x -> x~ rows of HP (cols 0..1023)
__device__ __forceinline__ void cvt_x_body(int idx, const float* __restrict__ src,
                                           unsigned short* __restrict__ dst) {
    int row = idx >> 7, c8 = (idx & 127) * 8;
    const float4* s = (const float4*)(src + (size_t)row * H_DIM + c8);
    float4 a = s[0], b = s[1];
    ushort4 o0, o1;
    o0.x = f32_to_bf16_rn(a.x); o0.y = f32_to_bf16_rn(a.y);
    o0.z = f32_to_bf16_rn(a.z); o0.w = f32_to_bf16_rn(a.w);
    o1.x = f32_to_bf16_rn(b.x); o1.y = f32_to_bf16_rn(b.y);
    o1.z = f32_to_bf16_rn(b.z); o1.w = f32_to_bf16_rn(b.w);
    ushort4* d = (ushort4*)(dst + (size_t)row * HP + c8);
    d[0] = o0; d[1] = o1;
}

// cols 1024..1087 of x~: 1.0 at col 1024, zeros elsewhere  (idx over 16384*8)
__device__ __forceinline__ void fill_pad_body(int idx, unsigned short* __restrict__ dst) {
    int row = idx >> 3, c = idx & 7;
    uint4 v; v.x = (c == 0) ? 0x00003F80u : 0u; v.y = 0u; v.z = 0u; v.w = 0u;
    *(uint4*)(dst + (size_t)row * HP + 1024 + c * 8) = v;
}

// zero the never-written band regions of pb: per batch, qtile ql=0 cols 0..511,
// ql=1 cols 0..255.  12 regions of 256x256, idx over 12*8192.
__device__ __forceinline__ void zero_pb_body(int idx, unsigned short* __restrict__ pb) {
    int r = idx >> 13;
    int rem = idx & 8191;
    int row = rem >> 5, c8 = (rem & 31) * 8;
    int batch = r / 3, sub = r % 3;
    int qt = batch * 16 + (sub == 2 ? 1 : 0);
    int col0 = (sub == 2 ? 0 : sub * 256);
    uint4 z; z.x = 0u; z.y = 0u; z.z = 0u; z.w = 0u;
    *(uint4*)(pb + (size_t)qt * (256 * 768) + (size_t)row * 768 + col0 + c8) = z;
}

// W (f32) + bias -> [W^T ; bias ; 0] bf16, nrows x 1024.  (bx in [0,8), by in [0,nby))
__device__ __forceinline__ void tr_cvt_body(float (&Lt)[128][33],
                                            const float* __restrict__ Wsrc,
                                            const float* __restrict__ bias,
                                            unsigned short* __restrict__ dst,
                                            int bx, int by, int tid) {
    if (by >= 32) {                                // rows >=1024: bias row + zeros
        if (bx != 0) return;
        const int h0 = by * 32;
#pragma unroll
        for (int i = 0; i < 128; ++i) {
            int idx = i * 256 + tid;               // 32*1024
            int r = idx >> 10, cc = idx & 1023;
            int h = h0 + r;
            float v = (h == 1024) ? bias[cc] : 0.0f;
            dst[(size_t)h * 1024 + cc] = f32_to_bf16_rn(v);
        }
        return;
    }
    const int w0 = bx * 128, h0 = by * 32;
#pragma unroll
    for (int i = 0; i < 16; ++i) {
        int idx = i * 256 + tid;
        int r = idx >> 5, cc = idx & 31;
        Lt[r][cc] = Wsrc[(size_t)(w0 + r) * 1024 + h0 + cc];
    }
    __syncthreads();
#pragma unroll
    for (int i = 0; i < 16; ++i) {
        int idx = i * 256 + tid;
        int hh = idx >> 7, ww = idx & 127;
        dst[(size_t)(h0 + hh) * 1024 + w0 + ww] = f32_to_bf16_rn(Lt[ww][hh]);
    }
}

// ---------------------------------------------------------------- 128x128 GEMM (P1 only)
__device__ __forceinline__ void gemm_body128(unsigned short (&As)[2][128 * 32],
                                             unsigned short (&Bs)[2][128 * 32],
                                             int bx, int by,
                                             const unsigned short* __restrict__ A, int lda,
                                             const unsigned short* __restrict__ W, int ldw,
                                             unsigned short* __restrict__ outp, int ldo,
                                             int K, int p0) {
    const int tid  = threadIdx.x;
    const int lane = tid & 63;
    const int w4   = tid >> 6;
    const int wm   = w4 >> 1, wn = w4 & 1;
    const int l15  = lane & 15;
    const int q8   = (lane >> 4) * 8;
    const int q4   = (lane >> 4) * 4;

    const int aRow0 = by * 128, wRow0 = bx * 128;

    floatx4 acc[4][4];
#pragma unroll
    for (int i = 0; i < 4; ++i)
#pragma unroll
        for (int j = 0; j < 4; ++j) acc[i][j] = (floatx4)0.0f;

    for (int k0 = 0; k0 < K; k0 += 64) {
        __syncthreads();
#pragma unroll
        for (int p = 0; p < 2; ++p) {
            const int c = p * 256 + tid;
            const unsigned short* gA = A + (size_t)(aRow0 + (c >> 2)) * lda + k0 + (c & 3) * 8;
            const unsigned short* gW = W + (size_t)(wRow0 + (c >> 2)) * ldw + k0 + (c & 3) * 8;
            char* dA0 = (char*)&As[0][0] + (size_t)(p * 256 + w4 * 64) * 16;
            char* dA1 = (char*)&As[1][0] + (size_t)(p * 256 + w4 * 64) * 16;
            char* dB0 = (char*)&Bs[0][0] + (size_t)(p * 256 + w4 * 64) * 16;
            char* dB1 = (char*)&Bs[1][0] + (size_t)(p * 256 + w4 * 64) * 16;
            GLOAD_LDS16(gA,      dA0);
            GLOAD_LDS16(gA + 32, dA1);
            GLOAD_LDS16(gW,      dB0);
            GLOAD_LDS16(gW + 32, dB1);
        }
        __syncthreads();

#pragma unroll
        for (int h = 0; h < 2; ++h) {
            short8 af[4], bf[4];
#pragma unroll
            for (int mt = 0; mt < 4; ++mt)
                af[mt] = *(const short8*)(&As[h][0] + (wm * 64 + mt * 16 + l15) * 32 + q8);
#pragma unroll
            for (int nt = 0; nt < 4; ++nt)
                bf[nt] = *(const short8*)(&Bs[h][0] + (wn * 64 + nt * 16 + l15) * 32 + q8);
#pragma unroll
            for (int mt = 0; mt < 4; ++mt)
#pragma unroll
                for (int nt = 0; nt < 4; ++nt)
                    acc[mt][nt] = MFMA(af[mt], bf[nt], acc[mt][nt]);
        }
    }

#pragma unroll
    for (int nt = 0; nt < 4; ++nt) {
        const int ol = wn * 64 + nt * 16 + l15;
#pragma unroll
        for (int mt = 0; mt < 4; ++mt) {
#pragma unroll
            for (int r = 0; r < 4; ++r) {
                const int nl = wm * 64 + mt * 16 + q4 + r;
                const int o = wRow0 + ol;
                if (o < p0)
                    outp[(size_t)(aRow0 + nl) * ldo + o] = f32_to_bf16_rn(acc[mt][nt][r]);
            }
        }
    }
}

// ---------------------------------------------------------------- 256x256 8-wave K64-tile GEMM
// C[m,n] = sum_k A[m,k]*W[n,k].  K as NT tiles of 64; 2 LDS buffers (t&1), each
// A[256x64] + B[256x64].  Per tile 4 phases (quadrants (0,0),(0,1),(1,1),(1,0)),
// m201 phase shape: {ds_reads pre-barrier; BAR; stage-issue + 16 MFMA; BAR}.
// One counted vmcnt(4) per tile at ph4 (see header).  T2 swizzle ch^=(row&7):
// linear LDS dest for gload_lds, inverse-swizzled global source, swizzled read.
// MODE 0: G   (bf16 store, col-clip HP)    MODE 1: Vt  (scatter to [b][h][s])
// MODE 2: Pb  (decay epilogue -> band)     MODE 3: out (f32 store, banded K)
template <int MODE, int NT>
__device__ __forceinline__ void g256_body(unsigned short (&lds)[2][2][16384],
                                          int bx, int by,
                                          const unsigned short* __restrict__ Abase, int lda,
                                          const unsigned short* __restrict__ Wbase, int ldw,
                                          void* __restrict__ outp) {
    const int tid  = threadIdx.x;
    const int lane = tid & 63;
    const int wv   = tid >> 6;         // 0..7
    const int wm   = wv >> 2, wn = wv & 3;
    const int l15  = lane & 15;
    const int q    = lane >> 4;        // 0..3 (8-elem chunk within 32-k step)
    const int q4   = q * 4;

    const unsigned short* Ap;
    const unsigned short* Wp;
    int ql = 0;
    if (MODE == 0) {
        Ap = Abase + (size_t)(by * 256) * lda;
        Wp = Wbase + (size_t)(bx * 256) * ldw;
    } else if (MODE == 1) {
        Ap = Abase + (size_t)(bx * 256) * lda;         // h-tile
        Wp = Wbase + (size_t)(by * 256) * ldw;         // s-tile
    } else if (MODE == 2) {
        ql = by & 15;
        const int j256 = ql - 2 + bx;
        if (j256 < 0) return;                           // block-uniform early exit
        Ap = Abase + (size_t)(by * 256) * lda;
        Wp = Wbase + (size_t)((by >> 4) * S_LEN + j256 * 256) * ldw;
    } else {                                            // MODE 3
        ql = by & 15;
        Ap = Abase + (size_t)by * (256 * 768);
        Wp = Wbase + ((ptrdiff_t)((by >> 4) * H_DIM + bx * 256)) * S_LEN
                   + ((ptrdiff_t)ql - 2) * 256;         // may be negative: reads x Pb zeros
    }

    floatx4 acc[8][4];
#pragma unroll
    for (int i = 0; i < 8; ++i)
#pragma unroll
        for (int j = 0; j < 4; ++j) acc[i][j] = (floatx4)0.0f;

    // stage one matrix (256x64 = 2048 chunks of 16B) of tile t into lds[t&1][m].
    // LDS dest linear (chunk c at byte c*16); source chunk = (c&7)^(row&7).
    auto STAGE2 = [&](int t, int m) {
        const int b  = t & 1;
        const int k0 = t * 64;
        const unsigned short* gp = m ? Wp : Ap;
        const int ld = m ? ldw : lda;
        char* base = (char*)&lds[b][m][0];
#pragma unroll
        for (int i = 0; i < 4; ++i) {
            const int c   = i * 512 + tid;
            const int row = c >> 3;
            const int ch  = (c & 7) ^ (row & 7);
            GLOAD_LDS16(gp + (size_t)row * ld + k0 + ch * 8,
                        base + (size_t)(i * 512 + wv * 64) * 16);
        }
    };

    short8 afr[4][2], bfr[2][2];
    auto RDA = [&](int t, int mh) {
        const unsigned short* base = &lds[t & 1][0][0];
#pragma unroll
        for (int mt = 0; mt < 4; ++mt) {
            const int r = wm * 128 + mh * 64 + mt * 16 + l15;
#pragma unroll
            for (int h = 0; h < 2; ++h) {
                const int ch = (h * 4 + q) ^ (r & 7);
                afr[mt][h] = *(const short8*)(base + r * 64 + ch * 8);
            }
        }
    };
    auto RDB = [&](int t, int nh) {
        const unsigned short* base = &lds[t & 1][1][0];
#pragma unroll
        for (int nt = 0; nt < 2; ++nt) {
            const int r = wn * 64 + (nh * 2 + nt) * 16 + l15;
#pragma unroll
            for (int h = 0; h < 2; ++h) {
                const int ch = (h * 4 + q) ^ (r & 7);
                bfr[nt][h] = *(const short8*)(base + r * 64 + ch * 8);
            }
        }
    };
    auto QMFMA = [&](int mh, int nh) {
        __builtin_amdgcn_s_setprio(1);
#pragma unroll
        for (int mt = 0; mt < 4; ++mt)
#pragma unroll
            for (int nt = 0; nt < 2; ++nt)
#pragma unroll
                for (int h = 0; h < 2; ++h)
                    acc[mh * 4 + mt][nh * 2 + nt] =
                        MFMA(afr[mt][h], bfr[nt][h], acc[mh * 4 + mt][nh * 2 + nt]);
        __builtin_amdgcn_s_setprio(0);
    };

    // prologue: A(0),B(0) resident; A(1) in flight.  Queue after: [A1]=4.
    STAGE2(0, 0);
    STAGE2(0, 1);
    if (NT > 1) STAGE2(1, 0);
    asm volatile("s_waitcnt vmcnt(4)" ::: "memory");
    BAR();

#pragma unroll 1
    for (int t = 0; t < NT; ++t) {
        const bool sB = (t + 1 < NT);   // stage B(t+1) at ph1
        const bool sA = (t + 2 < NT);   // stage A(t+2) at ph4
        // ---- ph1: quadrant (0,0)
        RDA(t, 0);
        RDB(t, 0);
        BAR();
        if (sB) STAGE2(t + 1, 1);
        QMFMA(0, 0);
        BAR();
        // ---- ph2: quadrant (0,1)  (A regs kept)
        RDB(t, 1);
        BAR();
        QMFMA(0, 1);
        BAR();
        // ---- ph3: quadrant (1,1)  (B regs kept)
        RDA(t, 1);
        BAR();
        QMFMA(1, 1);
        BAR();
        // ---- ph4: quadrant (1,0)  (re-read B q0)
        RDB(t, 0);
        BAR();
        if (sA) STAGE2(t + 2, 0);
        QMFMA(1, 0);
        // ledger: Q=[A(t+1),B(t+1),A(t+2)]=12 -> vmcnt(4) drains exactly what
        // tile t+1 ph1 reads; A(t+2) stays in flight.
        if (sA) {
            asm volatile("s_waitcnt vmcnt(4)" ::: "memory");
        } else if (sB) {
            asm volatile("s_waitcnt vmcnt(0)" ::: "memory");
        }
        BAR();
    }

    // ---- epilogue (C/D layout: col=lane&15, row=(lane>>4)*4+r)
#pragma unroll
    for (int nt = 0; nt < 4; ++nt) {
        const int ol = wn * 64 + nt * 16 + l15;          // n-local 0..255
#pragma unroll
        for (int mt = 0; mt < 8; ++mt) {
#pragma unroll
            for (int r = 0; r < 4; ++r) {
                const int nl = wm * 128 + mt * 16 + q4 + r;   // m-local 0..255
                const float v = acc[mt][nt][r];
                if (MODE == 0) {
                    const int o = bx * 256 + ol;
                    if (o < HP)
                        ((unsigned short*)outp)[(size_t)(by * 256 + nl) * HP + o] =
                            f32_to_bf16_rn(v);
                } else if (MODE == 1) {
                    const int s  = by * 256 + ol;
                    const int hh = bx * 256 + nl;
                    ((unsigned short*)outp)[((size_t)(s >> 12) * H_DIM + hh) * S_LEN +
                                            (s & (S_LEN - 1))] = f32_to_bf16_rn(v);
                } else if (MODE == 2) {
                    const int d = (2 - bx) * 256 + nl - ol;
                    const float pv = (d >= 0) ? v * exp2f((float)d * LOG2G) : 0.0f;
                    ((unsigned short*)outp)[(size_t)by * (256 * 768) + (size_t)nl * 768 +
                                            bx * 256 + ol] = f32_to_bf16_rn(pv);
                } else {
                    ((float*)outp)[(size_t)(by * 256 + nl) * H_DIM + bx * 256 + ol] = v;
                }
            }
        }
    }
}

// ---------------------------------------------------------------- launches
// L1: all prep: tr_cvt(Wq 1152r), tr_cvt(Wk 1280r), cvt Wv, zero pb band, x~ pad cols
__global__ __launch_bounds__(256) void prep_small(const float* __restrict__ Wq,
                                                  const float* __restrict__ bq,
                                                  const float* __restrict__ Wk,
                                                  const float* __restrict__ bk,
                                                  const float* __restrict__ Wv,
                                                  unsigned short* __restrict__ wqT,
                                                  unsigned short* __restrict__ wkT,
                                                  unsigned short* __restrict__ wvb,
                                                  unsigned short* __restrict__ pb,
                                                  unsigned short* __restrict__ xtb) {
    __shared__ float Lt[128][33];
    const int t = blockIdx.x, tid = threadIdx.x;
    if (t < 288) {
        tr_cvt_body(Lt, Wq, bq, wqT, t & 7, t >> 3, tid);             // by 0..35
    } else if (t < 608) {
        const int t2 = t - 288;
        tr_cvt_body(Lt, Wk, bk, wkT, t2 & 7, t2 >> 3, tid);           // by 0..39
    } else if (t < 1632) {
        cvt_bf16_body((t - 608) * 256 + tid, Wv, wvb, H_DIM * H_DIM / 4);
    } else if (t < 2016) {
        zero_pb_body((t - 1632) * 256 + tid, pb);
    } else {
        fill_pad_body((t - 2016) * 256 + tid, xtb);
    }
}

// L2: P1 (90 latency-bound blocks, first) ∪ cvt_x (8192 streaming blocks hide it)
__global__ __launch_bounds__(256) void cvtx_p1(const float* __restrict__ x,
                                               unsigned short* __restrict__ xtb,
                                               const unsigned short* __restrict__ wkT,
                                               const unsigned short* __restrict__ wqT,
                                               unsigned short* __restrict__ p1) {
    __shared__ unsigned short As[2][128 * 32];
    __shared__ unsigned short Bs[2][128 * 32];
    const int t = blockIdx.x;
    if (t < 90) {
        // P1 = W~kT . W~qT^T  (1280 x 1152 clipped to 1088 cols, K=1024)
        gemm_body128(As, Bs, t % 9, t / 9, wkT, 1024, wqT, 1024, p1, HP, 1024, HP);
    } else {
        cvt_x_body((t - 90) * 256 + threadIdx.x, x, xtb);
    }
}

// L3: G = x~ . P1^T  (16384 x 1280 -> clip 1088, K=1088 = 17 tiles), XCD-swizzled
__global__ __launch_bounds__(512, 2) void g256_g(const unsigned short* __restrict__ xtb,
                                                 const unsigned short* __restrict__ p1,
                                                 unsigned short* __restrict__ gb) {
    __shared__ unsigned short lds[2][2][16384];
    const int bid = blockIdx.x;                 // 320 = 8 * 40
    const int g = bid & 7, j = bid >> 3;
    g256_body<0, 17>(lds, j % 5, g * 8 + j / 5, xtb, HP, p1, HP, gb);
}

// L4: Pb (192 blocks, latency-exposed — first) ∪ Vt (256 blocks behind them)
__global__ __launch_bounds__(512, 2) void g256_pbvt(const unsigned short* __restrict__ gb,
                                                    const unsigned short* __restrict__ xtb,
                                                    const unsigned short* __restrict__ wvb,
                                                    unsigned short* __restrict__ pb,
                                                    unsigned short* __restrict__ vtb) {
    __shared__ unsigned short lds[2][2][16384];
    const int t = blockIdx.x;
    if (t < 192) {
        // Pb = band(G . x~^T) * gamma^d  (3 slots of 256 per q-tile, K=1088)
        const int g = t & 7, j = t >> 3;        // 192 = 8 * 24
        g256_body<2, 17>(lds, j % 3, g * 8 + j / 3, gb, HP, xtb, HP, pb);
    } else {
        // Vt = Wv . x~^T scattered to [b][h][s]  (K=1024 = 16 tiles)
        const int t2 = t - 192;
        const int g = t2 & 7, j = t2 >> 3;      // 256 = 8 * 32
        g256_body<1, 16>(lds, j & 3, g * 8 + (j >> 2), wvb, 1024, xtb, HP, vtb);
    }
}

// L5: out = Pb . Vt^T  (K=768 = 12 tiles, f32)
__global__ __launch_bounds__(512, 2) void g256_out(const unsigned short* __restrict__ pb,
                                                   const unsigned short* __restrict__ vtb,
                                                   float* __restrict__ out) {
    __shared__ unsigned short lds[2][2][16384];
    const int bid = blockIdx.x;                 // 256 = 8 * 32
    const int g = bid & 7, j = bid >> 3;
    g256_body<3, 12>(lds, j & 3, g * 8 + (j >> 2), pb, 768, vtb, S_LEN, out);
}

// ---------------------------------------------------------------- launcher
extern "C" void kernel_launch(void* const* d_in, const int* in_sizes, int n_in,
                              void* d_out, int out_size, void* d_ws, size_t ws_size,
                              hipStream_t stream) {
    (void)in_sizes; (void)n_in; (void)out_size; (void)ws_size;

    const float* x  = (const float*)d_in[0];
    const float* Wq = (const float*)d_in[1];
    const float* bq = (const float*)d_in[2];
    const float* Wk = (const float*)d_in[3];
    const float* bk = (const float*)d_in[4];
    const float* Wv = (const float*)d_in[5];
    float* out = (float*)d_out;

    unsigned short* xtb = (unsigned short*)d_ws;                    // 16384*1088*2 = 35.7 MB
    unsigned short* gb  = xtb + (size_t)NROWS * HP;                 // 35.7 MB
    unsigned short* vtb = gb  + (size_t)NROWS * HP;                 // 33.6 MB
    unsigned short* pb  = vtb + (size_t)NROWS * H_DIM;              // 64*256*768*2 = 25.2 MB
    unsigned short* wqT = pb  + (size_t)64 * 256 * 768;             // 1152*1024*2 = 2.36 MB
    unsigned short* wkT = wqT + (size_t)1152 * 1024;                // 1280*1024*2 = 2.62 MB
    unsigned short* p1  = wkT + (size_t)1280 * 1024;                // 1280*1088*2 = 2.79 MB
    unsigned short* wvb = p1  + (size_t)1280 * HP;                  // 2.1 MB
    // total ~= 140 MB

    prep_small<<<2528, 256, 0, stream>>>(Wq, bq, Wk, bk, Wv, wqT, wkT, wvb, pb, xtb);
    cvtx_p1<<<90 + 8192, 256, 0, stream>>>(x, xtb, wkT, wqT, p1);
    g256_g<<<320, 512, 0, stream>>>(xtb, p1, gb);
    g256_pbvt<<<192 + 256, 512, 0, stream>>>(gb, xtb, wvb, pb, vtb);
    g256_out<<<256, 512, 0, stream>>>(pb, vtb, out);
}

// Round 5
// 307.674 us; speedup vs baseline: 1.0736x; 1.0708x over previous
//
#include <hip/hip_runtime.h>

// Retention, B=4 S=4096 H=1024, gamma=0.96875.
// out[b,i,:] = sum_{j<=i} gamma^(i-j) * (q_i . k_j) * v_j
//
// Pipeline:
//   x~   = [x | 1 | 0pad63]               (16384 x 1088 bf16)
//   W~qT = [Wq^T ; bq ; 0pad]             (1152 x 1024)   W~kT same, padded to 1280 rows
//   P1   = W~kT . W~qT^T                  (1280 x 1088)   (128^2 kernel, hidden under cvt_x)
//   G    = x~ . P1^T                      (16384 x 1280, cols >=1088 are 0, clipped store)
//   Vt   = (Wv . x~^T) scattered          ([b][h][s] bf16)
//   Pb   = band(G . x~^T) * gamma^d       (64 qtiles x 256 x 768 bf16, 3 key-slots of 256)
//   out  = Pb . Vt^T (K=768 banded)       (f32)
// Band window 512..767 (>= old 512); truncated tail < 1e-5 << threshold.
//
// R5 change: the epilogue, not the K-loop, was the bottleneck.  R1-R4 all stored
// C as 64-128 scattered 2B stores/thread (65536 store-insts/block ~ 16K cyc/SIMD
// vs 10.5K of MFMA; WRITE_SIZE showed 1.43x amplification).  Now: LDS-transpose
// epilogue — acc -> swizzled 256x256 bf16 image in the (free) staging LDS
// (col ^= ((row>>2)&3)<<4, q-groups on disjoint bank octets), barrier, then 16
// coalesced 16B stores/thread (8192 full-line stores/block, 8x fewer insts).
// MODE 3 (f32) runs two 128-row passes.  Also: B held fully in regs (bfr[4][2],
// no ph4 re-read; 24 ds_read_b128/tile, 6 barriers/tile), MODE 2 decay via
// gamma^(C+row)*gamma^(-col) tables (36 exp2f vs 128).  K-loop schedule, counted
// vmcnt(4)/tile, grids and fusion unchanged from R4.

typedef __attribute__((ext_vector_type(8))) short short8;   // 8 bf16 = 4 VGPRs
typedef __attribute__((ext_vector_type(4))) float floatx4;  // MFMA 16x16 C/D

#define MFMA(a, b, c) __builtin_amdgcn_mfma_f32_16x16x32_bf16((a), (b), (c), 0, 0, 0)

#define B_SZ   4
#define S_LEN  4096
#define H_DIM  1024
#define NROWS  (B_SZ * S_LEN)          // 16384
#define HP     1088                    // padded H+1 (17*64)
#define LOG2G  (-0.045803690f)         // log2(0.96875)

__device__ __forceinline__ unsigned short f32_to_bf16_rn(float f) {
    unsigned int u = __float_as_uint(f);
    u += 0x7FFFu + ((u >> 16) & 1u);   // round-to-nearest-even
    return (unsigned short)(u >> 16);
}

#define GLOAD_LDS16(gptr, lptr)                                                        \
    __builtin_amdgcn_global_load_lds((__attribute__((address_space(1))) void*)(gptr),  \
                                     (__attribute__((address_space(3))) void*)(lptr),  \
                                     16, 0, 0)

#define BAR()                                   \
    do {                                        \
        asm volatile("" ::: "memory");          \
        __builtin_amdgcn_s_barrier();           \
        asm volatile("" ::: "memory");          \
    } while (0)

// ---------------------------------------------------------------- elementwise bodies
__device__ __forceinline__ void cvt_bf16_body(int i, const float* __restrict__ src,
                                              unsigned short* __restrict__ dst, int n4) {
    if (i >= n4) return;
    float4 v = ((const float4*)src)[i];
    ushort4 o;
    o.x = f32_to_bf16_rn(v.x);
    o.y = f32_to_bf16_rn(v.y);
    o.z = f32_to_bf16_rn(v.z);
    o.w = f32_to_bf16_rn(v.w);
    ((ushort4*)dst)[i] = o;
}

// x -> x~ rows of HP (cols 0..1023)
__device__ __forceinline__ void cvt_x_body(int idx, const float* __restrict__ src,
                                           unsigned short* __restrict__ dst) {
    int row = idx >> 7, c8 = (idx & 127) * 8;
    const float4* s = (const float4*)(src + (size_t)row * H_DIM + c8);
    float4 a = s[0], b = s[1];
    ushort4 o0, o1;
    o0.x = f32_to_bf16_rn(a.x); o0.y = f32_to_bf16_rn(a.y);
    o0.z = f32_to_bf16_rn(a.z); o0.w = f32_to_bf16_rn(a.w);
    o1.x = f32_to_bf16_rn(b.x); o1.y = f32_to_bf16_rn(b.y);
    o1.z = f32_to_bf16_rn(b.z); o1.w = f32_to_bf16_rn(b.w);
    ushort4* d = (ushort4*)(dst + (size_t)row * HP + c8);
    d[0] = o0; d[1] = o1;
}

// cols 1024..1087 of x~: 1.0 at col 1024, zeros elsewhere  (idx over 16384*8)
__device__ __forceinline__ void fill_pad_body(int idx, unsigned short* __restrict__ dst) {
    int row = idx >> 3, c = idx & 7;
    uint4 v; v.x = (c == 0) ? 0x00003F80u : 0u; v.y = 0u; v.z = 0u; v.w = 0u;
    *(uint4*)(dst + (size_t)row * HP + 1024 + c * 8) = v;
}

// zero the never-written band regions of pb: per batch, qtile ql=0 cols 0..511,
// ql=1 cols 0..255.  12 regions of 256x256, idx over 12*8192.
__device__ __forceinline__ void zero_pb_body(int idx, unsigned short* __restrict__ pb) {
    int r = idx >> 13;
    int rem = idx & 8191;
    int row = rem >> 5, c8 = (rem & 31) * 8;
    int batch = r / 3, sub = r % 3;
    int qt = batch * 16 + (sub == 2 ? 1 : 0);
    int col0 = (sub == 2 ? 0 : sub * 256);
    uint4 z; z.x = 0u; z.y = 0u; z.z = 0u; z.w = 0u;
    *(uint4*)(pb + (size_t)qt * (256 * 768) + (size_t)row * 768 + col0 + c8) = z;
}

// W (f32) + bias -> [W^T ; bias ; 0] bf16, nrows x 1024.  (bx in [0,8), by in [0,nby))
__device__ __forceinline__ void tr_cvt_body(float (&Lt)[128][33],
                                            const float* __restrict__ Wsrc,
                                            const float* __restrict__ bias,
                                            unsigned short* __restrict__ dst,
                                            int bx, int by, int tid) {
    if (by >= 32) {                                // rows >=1024: bias row + zeros
        if (bx != 0) return;
        const int h0 = by * 32;
#pragma unroll
        for (int i = 0; i < 128; ++i) {
            int idx = i * 256 + tid;               // 32*1024
            int r = idx >> 10, cc = idx & 1023;
            int h = h0 + r;
            float v = (h == 1024) ? bias[cc] : 0.0f;
            dst[(size_t)h * 1024 + cc] = f32_to_bf16_rn(v);
        }
        return;
    }
    const int w0 = bx * 128, h0 = by * 32;
#pragma unroll
    for (int i = 0; i < 16; ++i) {
        int idx = i * 256 + tid;
        int r = idx >> 5, cc = idx & 31;
        Lt[r][cc] = Wsrc[(size_t)(w0 + r) * 1024 + h0 + cc];
    }
    __syncthreads();
#pragma unroll
    for (int i = 0; i < 16; ++i) {
        int idx = i * 256 + tid;
        int hh = idx >> 7, ww = idx & 127;
        dst[(size_t)(h0 + hh) * 1024 + w0 + ww] = f32_to_bf16_rn(Lt[ww][hh]);
    }
}

// ---------------------------------------------------------------- 128x128 GEMM (P1 only)
__device__ __forceinline__ void gemm_body128(unsigned short (&As)[2][128 * 32],
                                             unsigned short (&Bs)[2][128 * 32],
                                             int bx, int by,
                                             const unsigned short* __restrict__ A, int lda,
                                             const unsigned short* __restrict__ W, int ldw,
                                             unsigned short* __restrict__ outp, int ldo,
                                             int K, int p0) {
    const int tid  = threadIdx.x;
    const int lane = tid & 63;
    const int w4   = tid >> 6;
    const int wm   = w4 >> 1, wn = w4 & 1;
    const int l15  = lane & 15;
    const int q8   = (lane >> 4) * 8;
    const int q4   = (lane >> 4) * 4;

    const int aRow0 = by * 128, wRow0 = bx * 128;

    floatx4 acc[4][4];
#pragma unroll
    for (int i = 0; i < 4; ++i)
#pragma unroll
        for (int j = 0; j < 4; ++j) acc[i][j] = (floatx4)0.0f;

    for (int k0 = 0; k0 < K; k0 += 64) {
        __syncthreads();
#pragma unroll
        for (int p = 0; p < 2; ++p) {
            const int c = p * 256 + tid;
            const unsigned short* gA = A + (size_t)(aRow0 + (c >> 2)) * lda + k0 + (c & 3) * 8;
            const unsigned short* gW = W + (size_t)(wRow0 + (c >> 2)) * ldw + k0 + (c & 3) * 8;
            char* dA0 = (char*)&As[0][0] + (size_t)(p * 256 + w4 * 64) * 16;
            char* dA1 = (char*)&As[1][0] + (size_t)(p * 256 + w4 * 64) * 16;
            char* dB0 = (char*)&Bs[0][0] + (size_t)(p * 256 + w4 * 64) * 16;
            char* dB1 = (char*)&Bs[1][0] + (size_t)(p * 256 + w4 * 64) * 16;
            GLOAD_LDS16(gA,      dA0);
            GLOAD_LDS16(gA + 32, dA1);
            GLOAD_LDS16(gW,      dB0);
            GLOAD_LDS16(gW + 32, dB1);
        }
        __syncthreads();

#pragma unroll
        for (int h = 0; h < 2; ++h) {
            short8 af[4], bf[4];
#pragma unroll
            for (int mt = 0; mt < 4; ++mt)
                af[mt] = *(const short8*)(&As[h][0] + (wm * 64 + mt * 16 + l15) * 32 + q8);
#pragma unroll
            for (int nt = 0; nt < 4; ++nt)
                bf[nt] = *(const short8*)(&Bs[h][0] + (wn * 64 + nt * 16 + l15) * 32 + q8);
#pragma unroll
            for (int mt = 0; mt < 4; ++mt)
#pragma unroll
                for (int nt = 0; nt < 4; ++nt)
                    acc[mt][nt] = MFMA(af[mt], bf[nt], acc[mt][nt]);
        }
    }

#pragma unroll
    for (int nt = 0; nt < 4; ++nt) {
        const int ol = wn * 64 + nt * 16 + l15;
#pragma unroll
        for (int mt = 0; mt < 4; ++mt) {
#pragma unroll
            for (int r = 0; r < 4; ++r) {
                const int nl = wm * 64 + mt * 16 + q4 + r;
                const int o = wRow0 + ol;
                if (o < p0)
                    outp[(size_t)(aRow0 + nl) * ldo + o] = f32_to_bf16_rn(acc[mt][nt][r]);
            }
        }
    }
}

// ---------------------------------------------------------------- 256x256 8-wave K64-tile GEMM
// K-loop: K as NT tiles of 64; 2 LDS buffers (t&1); quadrant walk (0,0)(0,1)(1,1)(1,0),
// A per-half in regs (afr), B fully in regs (bfr, no re-read); reads issue pre-barrier;
// STAGE B(t+1) inside (0,0)'s MFMA slot, STAGE A(t+2) inside (1,0)'s; ONE counted
// vmcnt(4)/tile (ledger: [A(t+1),B(t+1),A(t+2)]=12 -> drains what t+1 ph1 reads).
// Epilogue: swizzled 256x256 LDS image (col ^= ((row>>2)&3)<<4), then 16 coalesced
// 16B stores/thread.  T2 staging swizzle ch^=(row&7); T5 setprio.
// MODE 0: G   (bf16, col-clip HP)    MODE 1: Vt  (scatter rows to [b][h][s])
// MODE 2: Pb  (decay -> band)        MODE 3: out (f32, two 128-row passes)
template <int MODE, int NT>
__device__ __forceinline__ void g256_body(unsigned short (&lds)[2][2][16384],
                                          int bx, int by,
                                          const unsigned short* __restrict__ Abase, int lda,
                                          const unsigned short* __restrict__ Wbase, int ldw,
                                          void* __restrict__ outp) {
    const int tid  = threadIdx.x;
    const int lane = tid & 63;
    const int wv   = tid >> 6;         // 0..7
    const int wm   = wv >> 2, wn = wv & 3;
    const int l15  = lane & 15;
    const int q    = lane >> 4;        // 0..3 (8-elem chunk within 32-k step)
    const int q4   = q * 4;

    const unsigned short* Ap;
    const unsigned short* Wp;
    int ql = 0;
    if (MODE == 0) {
        Ap = Abase + (size_t)(by * 256) * lda;
        Wp = Wbase + (size_t)(bx * 256) * ldw;
    } else if (MODE == 1) {
        Ap = Abase + (size_t)(bx * 256) * lda;         // h-tile
        Wp = Wbase + (size_t)(by * 256) * ldw;         // s-tile
    } else if (MODE == 2) {
        ql = by & 15;
        const int j256 = ql - 2 + bx;
        if (j256 < 0) return;                           // block-uniform early exit
        Ap = Abase + (size_t)(by * 256) * lda;
        Wp = Wbase + (size_t)((by >> 4) * S_LEN + j256 * 256) * ldw;
    } else {                                            // MODE 3
        ql = by & 15;
        Ap = Abase + (size_t)by * (256 * 768);
        Wp = Wbase + ((ptrdiff_t)((by >> 4) * H_DIM + bx * 256)) * S_LEN
                   + ((ptrdiff_t)ql - 2) * 256;         // may be negative: reads x Pb zeros
    }

    floatx4 acc[8][4];
#pragma unroll
    for (int i = 0; i < 8; ++i)
#pragma unroll
        for (int j = 0; j < 4; ++j) acc[i][j] = (floatx4)0.0f;

    // stage one matrix (256x64 = 2048 chunks of 16B) of tile t into lds[t&1][m].
    // LDS dest linear (chunk c at byte c*16); source chunk = (c&7)^(row&7).
    auto STAGE2 = [&](int t, int m) {
        const int b  = t & 1;
        const int k0 = t * 64;
        const unsigned short* gp = m ? Wp : Ap;
        const int ld = m ? ldw : lda;
        char* base = (char*)&lds[b][m][0];
#pragma unroll
        for (int i = 0; i < 4; ++i) {
            const int c   = i * 512 + tid;
            const int row = c >> 3;
            const int ch  = (c & 7) ^ (row & 7);
            GLOAD_LDS16(gp + (size_t)row * ld + k0 + ch * 8,
                        base + (size_t)(i * 512 + wv * 64) * 16);
        }
    };

    short8 afr[4][2], bfr[4][2];
    auto RDA = [&](int t, int mh) {
        const unsigned short* base = &lds[t & 1][0][0];
#pragma unroll
        for (int mt = 0; mt < 4; ++mt) {
            const int r = wm * 128 + mh * 64 + mt * 16 + l15;
#pragma unroll
            for (int h = 0; h < 2; ++h) {
                const int ch = (h * 4 + q) ^ (r & 7);
                afr[mt][h] = *(const short8*)(base + r * 64 + ch * 8);
            }
        }
    };
    auto RDB = [&](int t) {                             // all 4 B sub-tiles (both halves)
        const unsigned short* base = &lds[t & 1][1][0];
#pragma unroll
        for (int nt = 0; nt < 4; ++nt) {
            const int r = wn * 64 + nt * 16 + l15;
#pragma unroll
            for (int h = 0; h < 2; ++h) {
                const int ch = (h * 4 + q) ^ (r & 7);
                bfr[nt][h] = *(const short8*)(base + r * 64 + ch * 8);
            }
        }
    };
    auto QMFMA = [&](int mh, int nh) {
        __builtin_amdgcn_s_setprio(1);
#pragma unroll
        for (int mt = 0; mt < 4; ++mt)
#pragma unroll
            for (int nt = 0; nt < 2; ++nt)
#pragma unroll
                for (int h = 0; h < 2; ++h)
                    acc[mh * 4 + mt][nh * 2 + nt] =
                        MFMA(afr[mt][h], bfr[nh * 2 + nt][h], acc[mh * 4 + mt][nh * 2 + nt]);
        __builtin_amdgcn_s_setprio(0);
    };

    // prologue: A(0),B(0) resident; A(1) in flight.  Queue after wait: [A1]=4.
    STAGE2(0, 0);
    STAGE2(0, 1);
    if (NT > 1) STAGE2(1, 0);
    asm volatile("s_waitcnt vmcnt(4)" ::: "memory");
    BAR();

#pragma unroll 1
    for (int t = 0; t < NT; ++t) {
        const bool sB = (t + 1 < NT);   // stage B(t+1) in (0,0)'s slot
        const bool sA = (t + 2 < NT);   // stage A(t+2) in (1,0)'s slot
        // ---- (0,0): reads for A-half0 + all B issue pre-barrier
        RDA(t, 0);
        RDB(t);
        BAR();
        if (sB) STAGE2(t + 1, 1);
        QMFMA(0, 0);
        BAR();
        // ---- (0,1): pure MFMA (regs held)
        QMFMA(0, 1);
        BAR();
        // ---- (1,1): A-half1 reads pre-barrier
        RDA(t, 1);
        BAR();
        QMFMA(1, 1);
        BAR();
        // ---- (1,0): pure MFMA + stage + counted wait
        if (sA) STAGE2(t + 2, 0);
        QMFMA(1, 0);
        if (sA) {
            asm volatile("s_waitcnt vmcnt(4)" ::: "memory");
        } else if (sB) {
            asm volatile("s_waitcnt vmcnt(0)" ::: "memory");
        }
        BAR();
    }

    // ---- epilogue via swizzled LDS image + coalesced stores
    // (C/D frag: row = wm*128+mt*16+q4+r, col = wn*64+nt*16+l15)
    if (MODE != 3) {
        unsigned short* img = &lds[0][0][0];           // 256x256 bf16 = 128 KB
        float colf[4], rowf[8][4];
        if (MODE == 2) {
#pragma unroll
            for (int nt = 0; nt < 4; ++nt)
                colf[nt] = exp2f((float)(wn * 64 + nt * 16 + l15) * -LOG2G);   // g^-col
#pragma unroll
            for (int mt = 0; mt < 8; ++mt)
#pragma unroll
                for (int r = 0; r < 4; ++r)
                    rowf[mt][r] = exp2f(
                        (float)((2 - bx) * 256 + wm * 128 + mt * 16 + q4 + r) * LOG2G);
        }
#pragma unroll
        for (int mt = 0; mt < 8; ++mt) {
#pragma unroll
            for (int nt = 0; nt < 4; ++nt) {
#pragma unroll
                for (int r = 0; r < 4; ++r) {
                    const int row = wm * 128 + mt * 16 + q4 + r;
                    const int col = wn * 64 + nt * 16 + l15;
                    float v = acc[mt][nt][r];
                    if (MODE == 2) {
                        const int d = (2 - bx) * 256 + row - col;
                        v = (d >= 0) ? v * rowf[mt][r] * colf[nt] : 0.0f;
                    }
                    img[row * 256 + (col ^ (((row >> 2) & 3) << 4))] = f32_to_bf16_rn(v);
                }
            }
        }
        BAR();
#pragma unroll
        for (int i = 0; i < 16; ++i) {
            const int c   = i * 512 + tid;             // 8192 chunks of 16B
            const int row = c >> 5;
            const int c8  = (c & 31) * 8;
            short8 v = *(const short8*)&img[row * 256 + (c8 ^ (((row >> 2) & 3) << 4))];
            if (MODE == 0) {
                const int gc = bx * 256 + c8;
                if (gc < HP)
                    *(short8*)((unsigned short*)outp + (size_t)(by * 256 + row) * HP + gc) = v;
            } else if (MODE == 1) {
                const int s  = by * 256 + c8;
                const int hh = bx * 256 + row;
                *(short8*)((unsigned short*)outp +
                           ((size_t)(s >> 12) * H_DIM + hh) * S_LEN + (s & (S_LEN - 1))) = v;
            } else {                                   // MODE 2
                *(short8*)((unsigned short*)outp + (size_t)by * (256 * 768) +
                           (size_t)row * 768 + bx * 256 + c8) = v;
            }
        }
    } else {
        float* img32 = (float*)&lds[0][0][0];          // 128x256 f32 = 128 KB per pass
#pragma unroll
        for (int p = 0; p < 2; ++p) {
            if (p) BAR();                              // pass-0 reads done before overwrite
            if (wm == p) {
#pragma unroll
                for (int mt = 0; mt < 8; ++mt)
#pragma unroll
                    for (int nt = 0; nt < 4; ++nt)
#pragma unroll
                        for (int r = 0; r < 4; ++r) {
                            const int row = mt * 16 + q4 + r;          // 0..127
                            const int col = wn * 64 + nt * 16 + l15;
                            img32[row * 256 + (col ^ (((row >> 2) & 3) << 4))] =
                                acc[mt][nt][r];
                        }
            }
            BAR();
#pragma unroll
            for (int i = 0; i < 16; ++i) {
                const int c   = i * 512 + tid;         // 8192 chunks of 16B
                const int row = c >> 6;                // 0..127
                const int c4  = (c & 63) * 4;
                float4 v = *(const float4*)&img32[row * 256 +
                                                  (c4 ^ (((row >> 2) & 3) << 4))];
                *(float4*)((float*)outp + (size_t)(by * 256 + p * 128 + row) * H_DIM +
                           bx * 256 + c4) = v;
            }
        }
    }
}

// ---------------------------------------------------------------- launches
// L1: all prep: tr_cvt(Wq 1152r), tr_cvt(Wk 1280r), cvt Wv, zero pb band, x~ pad cols
__global__ __launch_bounds__(256) void prep_small(const float* __restrict__ Wq,
                                                  const float* __restrict__ bq,
                                                  const float* __restrict__ Wk,
                                                  const float* __restrict__ bk,
                                                  const float* __restrict__ Wv,
                                                  unsigned short* __restrict__ wqT,
                                                  unsigned short* __restrict__ wkT,
                                                  unsigned short* __restrict__ wvb,
                                                  unsigned short* __restrict__ pb,
                                                  unsigned short* __restrict__ xtb) {
    __shared__ float Lt[128][33];
    const int t = blockIdx.x, tid = threadIdx.x;
    if (t < 288) {
        tr_cvt_body(Lt, Wq, bq, wqT, t & 7, t >> 3, tid);             // by 0..35
    } else if (t < 608) {
        const int t2 = t - 288;
        tr_cvt_body(Lt, Wk, bk, wkT, t2 & 7, t2 >> 3, tid);           // by 0..39
    } else if (t < 1632) {
        cvt_bf16_body((t - 608) * 256 + tid, Wv, wvb, H_DIM * H_DIM / 4);
    } else if (t < 2016) {
        zero_pb_body((t - 1632) * 256 + tid, pb);
    } else {
        fill_pad_body((t - 2016) * 256 + tid, xtb);
    }
}

// L2: P1 (90 latency-bound blocks, first) ∪ cvt_x (8192 streaming blocks hide it)
__global__ __launch_bounds__(256) void cvtx_p1(const float* __restrict__ x,
                                               unsigned short* __restrict__ xtb,
                                               const unsigned short* __restrict__ wkT,
                                               const unsigned short* __restrict__ wqT,
                                               unsigned short* __restrict__ p1) {
    __shared__ unsigned short As[2][128 * 32];
    __shared__ unsigned short Bs[2][128 * 32];
    const int t = blockIdx.x;
    if (t < 90) {
        // P1 = W~kT . W~qT^T  (1280 x 1152 clipped to 1088 cols, K=1024)
        gemm_body128(As, Bs, t % 9, t / 9, wkT, 1024, wqT, 1024, p1, HP, 1024, HP);
    } else {
        cvt_x_body((t - 90) * 256 + threadIdx.x, x, xtb);
    }
}

// L3: G = x~ . P1^T  (16384 x 1280 -> clip 1088, K=1088 = 17 tiles), XCD-swizzled
__global__ __launch_bounds__(512, 2) void g256_g(const unsigned short* __restrict__ xtb,
                                                 const unsigned short* __restrict__ p1,
                                                 unsigned short* __restrict__ gb) {
    __shared__ unsigned short lds[2][2][16384];
    const int bid = blockIdx.x;                 // 320 = 8 * 40
    const int g = bid & 7, j = bid >> 3;
    g256_body<0, 17>(lds, j % 5, g * 8 + j / 5, xtb, HP, p1, HP, gb);
}

// L4: Pb (192 blocks, latency-exposed — first) ∪ Vt (256 blocks behind them)
__global__ __launch_bounds__(512, 2) void g256_pbvt(const unsigned short* __restrict__ gb,
                                                    const unsigned short* __restrict__ xtb,
                                                    const unsigned short* __restrict__ wvb,
                                                    unsigned short* __restrict__ pb,
                                                    unsigned short* __restrict__ vtb) {
    __shared__ unsigned short lds[2][2][16384];
    const int t = blockIdx.x;
    if (t < 192) {
        // Pb = band(G . x~^T) * gamma^d  (3 slots of 256 per q-tile, K=1088)
        const int g = t & 7, j = t >> 3;        // 192 = 8 * 24
        g256_body<2, 17>(lds, j % 3, g * 8 + j / 3, gb, HP, xtb, HP, pb);
    } else {
        // Vt = Wv . x~^T scattered to [b][h][s]  (K=1024 = 16 tiles)
        const int t2 = t - 192;
        const int g = t2 & 7, j = t2 >> 3;      // 256 = 8 * 32
        g256_body<1, 16>(lds, j & 3, g * 8 + (j >> 2), wvb, 1024, xtb, HP, vtb);
    }
}

// L5: out = Pb . Vt^T  (K=768 = 12 tiles, f32)
__global__ __launch_bounds__(512, 2) void g256_out(const unsigned short* __restrict__ pb,
                                                   const unsigned short* __restrict__ vtb,
                                                   float* __restrict__ out) {
    __shared__ unsigned short lds[2][2][16384];
    const int bid = blockIdx.x;                 // 256 = 8 * 32
    const int g = bid & 7, j = bid >> 3;
    g256_body<3, 12>(lds, j & 3, g * 8 + (j >> 2), pb, 768, vtb, S_LEN, out);
}

// ---------------------------------------------------------------- launcher
extern "C" void kernel_launch(void* const* d_in, const int* in_sizes, int n_in,
                              void* d_out, int out_size, void* d_ws, size_t ws_size,
                              hipStream_t stream) {
    (void)in_sizes; (void)n_in; (void)out_size; (void)ws_size;

    const float* x  = (const float*)d_in[0];
    const float* Wq = (const float*)d_in[1];
    const float* bq = (const float*)d_in[2];
    const float* Wk = (const float*)d_in[3];
    const float* bk = (const float*)d_in[4];
    const float* Wv = (const float*)d_in[5];
    float* out = (float*)d_out;

    unsigned short* xtb = (unsigned short*)d_ws;                    // 16384*1088*2 = 35.7 MB
    unsigned short* gb  = xtb + (size_t)NROWS * HP;                 // 35.7 MB
    unsigned short* vtb = gb  + (size_t)NROWS * HP;                 // 33.6 MB
    unsigned short* pb  = vtb + (size_t)NROWS * H_DIM;              // 64*256*768*2 = 25.2 MB
    unsigned short* wqT = pb  + (size_t)64 * 256 * 768;             // 1152*1024*2 = 2.36 MB
    unsigned short* wkT = wqT + (size_t)1152 * 1024;                // 1280*1024*2 = 2.62 MB
    unsigned short* p1  = wkT + (size_t)1280 * 1024;                // 1280*1088*2 = 2.79 MB
    unsigned short* wvb = p1  + (size_t)1280 * HP;                  // 2.1 MB
    // total ~= 140 MB

    prep_small<<<2528, 256, 0, stream>>>(Wq, bq, Wk, bk, Wv, wqT, wkT, wvb, pb, xtb);
    cvtx_p1<<<90 + 8192, 256, 0, stream>>>(x, xtb, wkT, wqT, p1);
    g256_g<<<320, 512, 0, stream>>>(xtb, p1, gb);
    g256_pbvt<<<192 + 256, 512, 0, stream>>>(gb, xtb, wvb, pb, vtb);
    g256_out<<<256, 512, 0, stream>>>(pb, vtb, out);
}